// Round 3
// baseline (1206.005 us; speedup 1.0000x reference)
//
#include <hip/hip_runtime.h>
#include <hip/hip_bf16.h>

// Problem dims (fixed by setup_inputs)
constexpr int BQ = 32;          // batch
constexpr int TT = 128;         // tokens
constexpr int DD = 13;          // depth
constexpr int E  = 1024;        // d_emb
constexpr int P  = 64;          // n_parts
constexpr int C  = 16;          // d_cap
constexpr int NC = 5;           // n_classes
constexpr int NI = TT * DD;     // 1664 input capsules (routing 1)
constexpr int NROWS = BQ * NI;  // 53248
constexpr int NCOL = 80;        // 64 part-cols + 13 depth-dot cols + 3 pad

// ---------------------------------------------------------------------------
// sumfa[b] = 13 * sum_t mask[b,t]   (fa = sigmoid(logit(m)) = m)
__global__ void k_sumfa(const float* __restrict__ mask, float* __restrict__ sumfa)
{
    const int b = blockIdx.x, tid = threadIdx.x;   // 128 threads
    float v = mask[b * TT + tid];
#pragma unroll
    for (int off = 32; off > 0; off >>= 1) v += __shfl_xor(v, off);
    __shared__ float p2[2];
    if ((tid & 63) == 0) p2[tid >> 6] = v;
    __syncthreads();
    if (tid == 0) sumfa[b] = (float)DD * (p2[0] + p2[1]);
}

// ---------------------------------------------------------------------------
// k0: precompute tables.
//  blocks 0..63   : p=blk -> c1t[p]=sum_k g*w, c2t[p]=sum_k b*w + dp_b,
//                   dwt[d][p]=sum_k de[d]*g*w
//  blocks 64..76  : d=blk-64 -> sde1[d]=sum de, sde2[d]=sum de^2
//  blocks 77..396 : wext[k][c]: c<64 -> g[k]*dp_w[c][k]; 64..76 -> de[c-64][k]; else 0
//  blocks 397..652: W1m[d][j*16+h] = W1[j][d][h]
__global__ void k0_pre(const float* __restrict__ ln_w, const float* __restrict__ ln_b,
                       const float* __restrict__ dp_w, const float* __restrict__ dp_b,
                       const float* __restrict__ depth_emb, const float* __restrict__ W1,
                       float* __restrict__ wext, float* __restrict__ W1m,
                       float* __restrict__ c1t, float* __restrict__ c2t,
                       float* __restrict__ dwt, float* __restrict__ sde1,
                       float* __restrict__ sde2)
{
    const int blk = blockIdx.x, tid = threadIdx.x;
    if (blk < 64) {
        __shared__ float red[15][256];
        const int p = blk;
        float accv[15];
#pragma unroll
        for (int c = 0; c < 15; ++c) accv[c] = 0.f;
        for (int k = tid; k < E; k += 256) {
            const float w = dp_w[(size_t)p * E + k];
            const float gw = ln_w[k] * w;
            accv[0] += gw;
            accv[1] += ln_b[k] * w;
#pragma unroll
            for (int d = 0; d < 13; ++d) accv[2 + d] += depth_emb[(size_t)d * E + k] * gw;
        }
#pragma unroll
        for (int c = 0; c < 15; ++c) red[c][tid] = accv[c];
        __syncthreads();
        if (tid < 15) {
            float s = 0.f;
            for (int t = 0; t < 256; ++t) s += red[tid][t];
            if (tid == 0)      c1t[p] = s;
            else if (tid == 1) c2t[p] = s + dp_b[p];
            else               dwt[(tid - 2) * 64 + p] = s;
        }
    } else if (blk < 77) {
        __shared__ float red[2][256];
        const int d = blk - 64;
        float s1 = 0.f, s2 = 0.f;
        for (int k = tid; k < E; k += 256) {
            const float v = depth_emb[(size_t)d * E + k];
            s1 += v; s2 += v * v;
        }
        red[0][tid] = s1; red[1][tid] = s2;
        __syncthreads();
        if (tid < 2) {
            float s = 0.f;
            for (int t = 0; t < 256; ++t) s += red[tid][t];
            if (tid == 0) sde1[d] = s; else sde2[d] = s;
        }
    } else if (blk < 77 + 320) {
        const int idx = (blk - 77) * 256 + tid;        // < 81920
        const int k = idx / NCOL, c = idx % NCOL;
        float v = 0.f;
        if (c < 64)      v = ln_w[k] * dp_w[(size_t)c * E + k];
        else if (c < 77) v = depth_emb[(size_t)(c - 64) * E + k];
        wext[idx] = v;
    } else {
        const int t = (blk - 397) * 256 + tid;         // < 65536
        const int d = t >> 10, col = t & 1023, j = col >> 4, h = col & 15;
        W1m[t] = W1[((size_t)j * 64 + d) * 16 + h];
    }
}

// ---------------------------------------------------------------------------
// k1a: streaming GEMM embs @ wext (+ in-loop row sums) -> LN folded epilogue
// -> swish -> mu written into V[row][960..1023]. One lane = one row.
__global__ __launch_bounds__(256) void
k1a(const float* __restrict__ embs, const float* __restrict__ wext,
    const float* __restrict__ c1t, const float* __restrict__ c2t,
    const float* __restrict__ dwt, const float* __restrict__ sde1,
    const float* __restrict__ sde2, float* __restrict__ V)
{
    const int row = blockIdx.x * 256 + threadIdx.x;
    const float* xr = embs + (size_t)row * E;
    float4 acc[20];
#pragma unroll
    for (int c = 0; c < 20; ++c) acc[c] = make_float4(0.f, 0.f, 0.f, 0.f);
    float s = 0.f, s2 = 0.f;

    for (int k0 = 0; k0 < E; k0 += 32) {
        float4 xb[8];
#pragma unroll
        for (int q = 0; q < 8; ++q)
            xb[q] = *reinterpret_cast<const float4*>(xr + k0 + q * 4);
#pragma unroll
        for (int q = 0; q < 8; ++q) {
            const float x0 = xb[q].x, x1 = xb[q].y, x2 = xb[q].z, x3 = xb[q].w;
            const float* wr = wext + (size_t)(k0 + q * 4) * NCOL;
#pragma unroll
            for (int c = 0; c < 20; ++c) {
                const float4 w0 = *reinterpret_cast<const float4*>(wr + c * 4);
                const float4 w1 = *reinterpret_cast<const float4*>(wr + NCOL + c * 4);
                const float4 w2 = *reinterpret_cast<const float4*>(wr + 2 * NCOL + c * 4);
                const float4 w3 = *reinterpret_cast<const float4*>(wr + 3 * NCOL + c * 4);
                acc[c].x = fmaf(x0, w0.x, fmaf(x1, w1.x, fmaf(x2, w2.x, fmaf(x3, w3.x, acc[c].x))));
                acc[c].y = fmaf(x0, w0.y, fmaf(x1, w1.y, fmaf(x2, w2.y, fmaf(x3, w3.y, acc[c].y))));
                acc[c].z = fmaf(x0, w0.z, fmaf(x1, w1.z, fmaf(x2, w2.z, fmaf(x3, w3.z, acc[c].z))));
                acc[c].w = fmaf(x0, w0.w, fmaf(x1, w1.w, fmaf(x2, w2.w, fmaf(x3, w3.w, acc[c].w))));
            }
            s += x0 + x1 + x2 + x3;
            s2 = fmaf(x0, x0, fmaf(x1, x1, fmaf(x2, x2, fmaf(x3, x3, s2))));
        }
    }

    const int d = row % DD;
    float deD = 0.f;
#pragma unroll
    for (int dd = 0; dd < 13; ++dd) {
        const int ci = (64 + dd) >> 2, mi = (64 + dd) & 3;
        const float v = (mi == 0) ? acc[ci].x : (mi == 1) ? acc[ci].y : (mi == 2) ? acc[ci].z : acc[ci].w;
        if (dd == d) deD = v;
    }
    const float mean = (s + sde1[d]) * (1.f / E);
    const float var = (s2 + 2.f * deD + sde2[d]) * (1.f / E) - mean * mean;
    const float rstd = rsqrtf(var + 1e-5f);
    const float* dwr = dwt + d * 64;
    float* mup = V + (size_t)row * 1024 + 960;
#pragma unroll
    for (int c = 0; c < 16; ++c) {
        const float4 ed = acc[c];
        const float4 dv = *reinterpret_cast<const float4*>(dwr + c * 4);
        const float4 cv1 = *reinterpret_cast<const float4*>(c1t + c * 4);
        const float4 cv2 = *reinterpret_cast<const float4*>(c2t + c * 4);
        float4 h, mu;
        h.x = fmaf(rstd, ed.x + dv.x - mean * cv1.x, cv2.x);
        h.y = fmaf(rstd, ed.y + dv.y - mean * cv1.y, cv2.y);
        h.z = fmaf(rstd, ed.z + dv.z - mean * cv1.z, cv2.z);
        h.w = fmaf(rstd, ed.w + dv.w - mean * cv1.w, cv2.w);
        mu.x = h.x / (1.f + __expf(-h.x));
        mu.y = h.y / (1.f + __expf(-h.y));
        mu.z = h.z / (1.f + __expf(-h.z));
        mu.w = h.w / (1.f + __expf(-h.w));
        *reinterpret_cast<float4*>(mup + c * 4) = mu;
    }
}

// ---------------------------------------------------------------------------
// k1b: V[row][col] = sum_d mu[row][d]*W1m[d][col] + B1[col], col=j*16+h.
// 16 rows/block, lane = col-quad; W strip in registers, mu broadcast from LDS.
__global__ __launch_bounds__(256) void
k1b(const float* __restrict__ W1m, const float* __restrict__ B1, float* __restrict__ V)
{
    __shared__ float muL[16][64];
    const int tid = threadIdx.x;
    const int row0 = blockIdx.x * 16;
#pragma unroll
    for (int q = 0; q < 4; ++q) {
        const int idx = q * 256 + tid;
        muL[idx >> 6][idx & 63] = V[(size_t)(row0 + (idx >> 6)) * 1024 + 960 + (idx & 63)];
    }
    __syncthreads();
    const int c4 = tid;   // col-quad 0..255
    float4 acc[16];
    const float4 bv = *reinterpret_cast<const float4*>(B1 + c4 * 4);
#pragma unroll
    for (int r = 0; r < 16; ++r) acc[r] = bv;

    for (int kc = 0; kc < 64; kc += 8) {
        float4 wreg[8];
#pragma unroll
        for (int kk = 0; kk < 8; ++kk)
            wreg[kk] = *reinterpret_cast<const float4*>(W1m + (size_t)(kc + kk) * 1024 + c4 * 4);
#pragma unroll
        for (int r = 0; r < 16; ++r) {
            const float4 ma = *reinterpret_cast<const float4*>(&muL[r][kc]);
            const float4 mb = *reinterpret_cast<const float4*>(&muL[r][kc + 4]);
            float4 a = acc[r];
            a.x = fmaf(ma.x, wreg[0].x, a.x); a.y = fmaf(ma.x, wreg[0].y, a.y);
            a.z = fmaf(ma.x, wreg[0].z, a.z); a.w = fmaf(ma.x, wreg[0].w, a.w);
            a.x = fmaf(ma.y, wreg[1].x, a.x); a.y = fmaf(ma.y, wreg[1].y, a.y);
            a.z = fmaf(ma.y, wreg[1].z, a.z); a.w = fmaf(ma.y, wreg[1].w, a.w);
            a.x = fmaf(ma.z, wreg[2].x, a.x); a.y = fmaf(ma.z, wreg[2].y, a.y);
            a.z = fmaf(ma.z, wreg[2].z, a.z); a.w = fmaf(ma.z, wreg[2].w, a.w);
            a.x = fmaf(ma.w, wreg[3].x, a.x); a.y = fmaf(ma.w, wreg[3].y, a.y);
            a.z = fmaf(ma.w, wreg[3].z, a.z); a.w = fmaf(ma.w, wreg[3].w, a.w);
            a.x = fmaf(mb.x, wreg[4].x, a.x); a.y = fmaf(mb.x, wreg[4].y, a.y);
            a.z = fmaf(mb.x, wreg[4].z, a.z); a.w = fmaf(mb.x, wreg[4].w, a.w);
            a.x = fmaf(mb.y, wreg[5].x, a.x); a.y = fmaf(mb.y, wreg[5].y, a.y);
            a.z = fmaf(mb.y, wreg[5].z, a.z); a.w = fmaf(mb.y, wreg[5].w, a.w);
            a.x = fmaf(mb.z, wreg[6].x, a.x); a.y = fmaf(mb.z, wreg[6].y, a.y);
            a.z = fmaf(mb.z, wreg[6].z, a.z); a.w = fmaf(mb.z, wreg[6].w, a.w);
            a.x = fmaf(mb.w, wreg[7].x, a.x); a.y = fmaf(mb.w, wreg[7].y, a.y);
            a.z = fmaf(mb.w, wreg[7].z, a.z); a.w = fmaf(mb.w, wreg[7].w, a.w);
            acc[r] = a;
        }
    }
#pragma unroll
    for (int r = 0; r < 16; ++r)
        *reinterpret_cast<float4*>(V + (size_t)(row0 + r) * 1024 + c4 * 4) = acc[r];
}

// ---------------------------------------------------------------------------
// k2: one routing-1 pass over V ([i][j*16+h] layout). Block=(b, 64-i tile),
// lane=j, wave=16 i. Named-register pipeline (no arrays -> no scratch).
__global__ __launch_bounds__(256) void
k2_pass(const float* __restrict__ V, const float* __restrict__ mask,
        const float* __restrict__ c1v, const float* __restrict__ ivv,
        const float* __restrict__ c0v, float* __restrict__ Smu,
        float* __restrict__ SV2, float* __restrict__ Dsum, const int it)
{
    __shared__ float lacc[P][34];
    const int tid = threadIdx.x, wave = tid >> 6, j = tid & 63;
    const int b = blockIdx.x / (NI / 64);
    const int tile = blockIdx.x % (NI / 64);
    for (int k = tid; k < P * 34; k += 256) (&lacc[0][0])[k] = 0.f;

    float4 C1a, C1b, C1c, C1d, IVa, IVb, IVc, IVd;
    float c0 = 0.f;
    C1a = C1b = C1c = C1d = IVa = IVb = IVc = IVd = make_float4(0.f, 0.f, 0.f, 0.f);
    if (it > 0) {
        const float4* cp = reinterpret_cast<const float4*>(c1v + ((size_t)b * P + j) * C);
        const float4* ip = reinterpret_cast<const float4*>(ivv + ((size_t)b * P + j) * C);
        C1a = cp[0]; C1b = cp[1]; C1c = cp[2]; C1d = cp[3];
        IVa = ip[0]; IVb = ip[1]; IVc = ip[2]; IVd = ip[3];
        c0 = c0v[(size_t)b * P + j];
    }
    const int i0 = tile * 64 + wave * 16;
    const float* vb = V + ((size_t)(b * NI) + i0) * 1024 + (j << 4);
    const float* mrow = mask + b * TT;

    float4 SMa, SMb, SMc, SMd, Qa, Qb, Qc, Qd;
    SMa = SMb = SMc = SMd = Qa = Qb = Qc = Qd = make_float4(0.f, 0.f, 0.f, 0.f);
    float dsum = 0.f;
    __syncthreads();

    auto proc = [&](const float4 va, const float4 vB, const float4 vc, const float4 vd, const int i) {
        float w;
        const float fam = mrow[i / DD];
        if (it > 0) {
            float q = c0;
            q = fmaf(va.x, fmaf(-va.x, IVa.x, C1a.x), q);
            q = fmaf(va.y, fmaf(-va.y, IVa.y, C1a.y), q);
            q = fmaf(va.z, fmaf(-va.z, IVa.z, C1a.z), q);
            q = fmaf(va.w, fmaf(-va.w, IVa.w, C1a.w), q);
            q = fmaf(vB.x, fmaf(-vB.x, IVb.x, C1b.x), q);
            q = fmaf(vB.y, fmaf(-vB.y, IVb.y, C1b.y), q);
            q = fmaf(vB.z, fmaf(-vB.z, IVb.z, C1b.z), q);
            q = fmaf(vB.w, fmaf(-vB.w, IVb.w, C1b.w), q);
            q = fmaf(vc.x, fmaf(-vc.x, IVc.x, C1c.x), q);
            q = fmaf(vc.y, fmaf(-vc.y, IVc.y, C1c.y), q);
            q = fmaf(vc.z, fmaf(-vc.z, IVc.z, C1c.z), q);
            q = fmaf(vc.w, fmaf(-vc.w, IVc.w, C1c.w), q);
            q = fmaf(vd.x, fmaf(-vd.x, IVd.x, C1d.x), q);
            q = fmaf(vd.y, fmaf(-vd.y, IVd.y, C1d.y), q);
            q = fmaf(vd.z, fmaf(-vd.z, IVd.z, C1d.z), q);
            q = fmaf(vd.w, fmaf(-vd.w, IVd.w, C1d.w), q);
            float m = q;
            m = fmaxf(m, __shfl_xor(m, 32));
            m = fmaxf(m, __shfl_xor(m, 16));
            m = fmaxf(m, __shfl_xor(m, 8));
            m = fmaxf(m, __shfl_xor(m, 4));
            m = fmaxf(m, __shfl_xor(m, 2));
            m = fmaxf(m, __shfl_xor(m, 1));
            const float e = __expf(q - m);
            float ss = e;
            ss += __shfl_xor(ss, 32);
            ss += __shfl_xor(ss, 16);
            ss += __shfl_xor(ss, 8);
            ss += __shfl_xor(ss, 4);
            ss += __shfl_xor(ss, 2);
            ss += __shfl_xor(ss, 1);
            w = fam * (e / ss);
        } else {
            w = fam * (1.f / 64.f);
        }
        dsum += w;
        SMa.x = fmaf(w, va.x, SMa.x); Qa.x = fmaf(w * va.x, va.x, Qa.x);
        SMa.y = fmaf(w, va.y, SMa.y); Qa.y = fmaf(w * va.y, va.y, Qa.y);
        SMa.z = fmaf(w, va.z, SMa.z); Qa.z = fmaf(w * va.z, va.z, Qa.z);
        SMa.w = fmaf(w, va.w, SMa.w); Qa.w = fmaf(w * va.w, va.w, Qa.w);
        SMb.x = fmaf(w, vB.x, SMb.x); Qb.x = fmaf(w * vB.x, vB.x, Qb.x);
        SMb.y = fmaf(w, vB.y, SMb.y); Qb.y = fmaf(w * vB.y, vB.y, Qb.y);
        SMb.z = fmaf(w, vB.z, SMb.z); Qb.z = fmaf(w * vB.z, vB.z, Qb.z);
        SMb.w = fmaf(w, vB.w, SMb.w); Qb.w = fmaf(w * vB.w, vB.w, Qb.w);
        SMc.x = fmaf(w, vc.x, SMc.x); Qc.x = fmaf(w * vc.x, vc.x, Qc.x);
        SMc.y = fmaf(w, vc.y, SMc.y); Qc.y = fmaf(w * vc.y, vc.y, Qc.y);
        SMc.z = fmaf(w, vc.z, SMc.z); Qc.z = fmaf(w * vc.z, vc.z, Qc.z);
        SMc.w = fmaf(w, vc.w, SMc.w); Qc.w = fmaf(w * vc.w, vc.w, Qc.w);
        SMd.x = fmaf(w, vd.x, SMd.x); Qd.x = fmaf(w * vd.x, vd.x, Qd.x);
        SMd.y = fmaf(w, vd.y, SMd.y); Qd.y = fmaf(w * vd.y, vd.y, Qd.y);
        SMd.z = fmaf(w, vd.z, SMd.z); Qd.z = fmaf(w * vd.z, vd.z, Qd.z);
        SMd.w = fmaf(w, vd.w, SMd.w); Qd.w = fmaf(w * vd.w, vd.w, Qd.w);
    };

    float4 A0, A1, A2, A3, B0, B1r, B2, B3;
    {
        const float4* p = reinterpret_cast<const float4*>(vb);
        A0 = p[0]; A1 = p[1]; A2 = p[2]; A3 = p[3];
    }
#pragma unroll
    for (int ss = 0; ss < 16; ss += 2) {
        {
            const float4* p = reinterpret_cast<const float4*>(vb + (size_t)(ss + 1) * 1024);
            B0 = p[0]; B1r = p[1]; B2 = p[2]; B3 = p[3];
        }
        proc(A0, A1, A2, A3, i0 + ss);
        if (ss + 2 < 16) {
            const float4* p = reinterpret_cast<const float4*>(vb + (size_t)(ss + 2) * 1024);
            A0 = p[0]; A1 = p[1]; A2 = p[2]; A3 = p[3];
        }
        proc(B0, B1r, B2, B3, i0 + ss + 1);
    }

    atomicAdd(&lacc[j][0],  SMa.x); atomicAdd(&lacc[j][1],  SMa.y);
    atomicAdd(&lacc[j][2],  SMa.z); atomicAdd(&lacc[j][3],  SMa.w);
    atomicAdd(&lacc[j][4],  SMb.x); atomicAdd(&lacc[j][5],  SMb.y);
    atomicAdd(&lacc[j][6],  SMb.z); atomicAdd(&lacc[j][7],  SMb.w);
    atomicAdd(&lacc[j][8],  SMc.x); atomicAdd(&lacc[j][9],  SMc.y);
    atomicAdd(&lacc[j][10], SMc.z); atomicAdd(&lacc[j][11], SMc.w);
    atomicAdd(&lacc[j][12], SMd.x); atomicAdd(&lacc[j][13], SMd.y);
    atomicAdd(&lacc[j][14], SMd.z); atomicAdd(&lacc[j][15], SMd.w);
    atomicAdd(&lacc[j][16], Qa.x);  atomicAdd(&lacc[j][17], Qa.y);
    atomicAdd(&lacc[j][18], Qa.z);  atomicAdd(&lacc[j][19], Qa.w);
    atomicAdd(&lacc[j][20], Qb.x);  atomicAdd(&lacc[j][21], Qb.y);
    atomicAdd(&lacc[j][22], Qb.z);  atomicAdd(&lacc[j][23], Qb.w);
    atomicAdd(&lacc[j][24], Qc.x);  atomicAdd(&lacc[j][25], Qc.y);
    atomicAdd(&lacc[j][26], Qc.z);  atomicAdd(&lacc[j][27], Qc.w);
    atomicAdd(&lacc[j][28], Qd.x);  atomicAdd(&lacc[j][29], Qd.y);
    atomicAdd(&lacc[j][30], Qd.z);  atomicAdd(&lacc[j][31], Qd.w);
    atomicAdd(&lacc[j][32], dsum);
    __syncthreads();

    for (int k = tid; k < P * 33; k += 256) {
        const int jj = k / 33, r = k % 33;
        const float v = lacc[jj][r];
        if (r < 16)      atomicAdd(&Smu[((size_t)b * P + jj) * C + r], v);
        else if (r < 32) atomicAdd(&SV2[((size_t)b * P + jj) * C + (r - 16)], v);
        else             atomicAdd(&Dsum[(size_t)b * P + jj], v);
    }
}

// ---------------------------------------------------------------------------
// k2f: finalize one routing-1 iteration; also zeroes the accumulators for the
// next pass. iv = 1/(2 sig2), c1 = 2*mu*iv, c0 = logsig(a)-0.5*sum log sig2 - sum mu^2*iv.
__global__ void k2f(float* __restrict__ Smu, float* __restrict__ SV2,
                    float* __restrict__ Dsum, const float* __restrict__ sumfa,
                    const float* __restrict__ bu, const float* __restrict__ bi,
                    float* __restrict__ muo, float* __restrict__ ivv,
                    float* __restrict__ c1v, float* __restrict__ c0v,
                    float* __restrict__ a1)
{
    const int t = blockIdx.x * blockDim.x + threadIdx.x;
    if (t >= BQ * P) return;
    const int b = t / P, j = t % P;
    const float ds = Dsum[t];
    const float inv = 1.f / ds;
    const float ao = bu[j] * ds - bi[j] * (sumfa[b] - ds);
    a1[t] = ao;
    const float lsg = (ao < 0.f) ? (ao - log1pf(__expf(ao))) : (-log1pf(__expf(-ao)));
    float sumlog = 0.f, moiv = 0.f;
#pragma unroll
    for (int h = 0; h < C; ++h) {
        const float m = Smu[t * C + h] * inv;
        const float s2 = fmaxf(SV2[t * C + h] * inv - m * m, 0.f) + 1e-5f;
        const float iv = 0.5f / s2;
        muo[t * C + h] = m;
        ivv[t * C + h] = iv;
        c1v[t * C + h] = 2.f * m * iv;
        sumlog += logf(s2);
        moiv += m * m * iv;
        Smu[t * C + h] = 0.f;
        SV2[t * C + h] = 0.f;
    }
    Dsum[t] = 0.f;
    c0v[t] = lsg - 0.5f * sumlog - moiv;
}

// ---------------------------------------------------------------------------
// K3: routing 2 (n_i=64, n_o=5, d=16) entirely inside one block per batch.
__global__ void k3_routing2(const float* __restrict__ muo, const float* __restrict__ a1,
                            const float* __restrict__ W2, const float* __restrict__ B2,
                            const float* __restrict__ bu2, const float* __restrict__ bi2,
                            float* __restrict__ out)
{
    __shared__ float mu1L[P][C];
    __shared__ float faL[P];
    __shared__ float V2L[P][NC][C];
    __shared__ float RL[P][NC];
    __shared__ float mu2L[NC][C];
    __shared__ float s2L[NC][C];
    __shared__ float isL[NC][C];
    __shared__ float dsL[NC];
    __shared__ float biasL[NC];
    __shared__ float a2L[NC];
    __shared__ float sumfa2s;
    const int b = blockIdx.x, tid = threadIdx.x;

    for (int k = tid; k < P * C; k += 256) (&mu1L[0][0])[k] = muo[(size_t)b * P * C + k];
    if (tid < P) {
        const float a = a1[(size_t)b * P + tid];
        faL[tid] = 1.f / (1.f + __expf(-a));
    }
    __syncthreads();
    if (tid == 0) {
        float s = 0.f;
        for (int i = 0; i < P; ++i) s += faL[i];
        sumfa2s = s;
    }
    {
        const int i = tid >> 2, hq = tid & 3;
        for (int jj = 0; jj < NC; ++jj) {
            float4 acc = *reinterpret_cast<const float4*>(B2 + jj * C + hq * 4);
            const float* wp = W2 + ((size_t)(i * NC + jj) * C) * C + hq * 4;
#pragma unroll
            for (int d = 0; d < C; ++d) {
                const float m = mu1L[i][d];
                const float4 w4 = *reinterpret_cast<const float4*>(wp + d * C);
                acc.x += m * w4.x; acc.y += m * w4.y; acc.z += m * w4.z; acc.w += m * w4.w;
            }
            *reinterpret_cast<float4*>(&V2L[i][jj][hq * 4]) = acc;
        }
    }
    __syncthreads();

    for (int it = 0; it < 3; ++it) {
        if (tid < P) {
            const int i = tid;
            if (it == 0) {
#pragma unroll
                for (int jj = 0; jj < NC; ++jj) RL[i][jj] = 1.f / NC;
            } else {
                float sc[NC];
                float m = -3.4e38f;
#pragma unroll
                for (int jj = 0; jj < NC; ++jj) {
                    float q = 0.f;
#pragma unroll
                    for (int h = 0; h < C; ++h) {
                        const float d = V2L[i][jj][h] - mu2L[jj][h];
                        q += d * d * isL[jj][h];
                    }
                    sc[jj] = biasL[jj] - q;
                    m = fmaxf(m, sc[jj]);
                }
                float sum = 0.f;
#pragma unroll
                for (int jj = 0; jj < NC; ++jj) { sc[jj] = __expf(sc[jj] - m); sum += sc[jj]; }
                const float invs = 1.f / sum;
#pragma unroll
                for (int jj = 0; jj < NC; ++jj) RL[i][jj] = sc[jj] * invs;
            }
        }
        __syncthreads();
        if (tid < NC) {
            float ds = 0.f;
            for (int i = 0; i < P; ++i) ds += faL[i] * RL[i][tid];
            dsL[tid] = ds;
        }
        __syncthreads();
        if (tid < NC * C) {
            const int jj = tid / C, h = tid % C;
            float smu = 0.f, sv2 = 0.f;
            for (int i = 0; i < P; ++i) {
                const float w = faL[i] * RL[i][jj];
                const float v = V2L[i][jj][h];
                smu += w * v;
                sv2 += w * v * v;
            }
            const float inv = 1.f / dsL[jj];
            const float m = smu * inv;
            const float s2 = fmaxf(sv2 * inv - m * m, 0.f) + 1e-5f;
            mu2L[jj][h] = m;
            s2L[jj][h] = s2;
            isL[jj][h] = 0.5f / s2;
        }
        __syncthreads();
        if (tid < NC) {
            const float ds = dsL[tid];
            const float ao = bu2[tid] * ds - bi2[tid] * (sumfa2s - ds);
            a2L[tid] = ao;
            const float lsg = (ao < 0.f) ? (ao - log1pf(__expf(ao))) : (-log1pf(__expf(-ao)));
            float sl = 0.f;
#pragma unroll
            for (int h = 0; h < C; ++h) sl += logf(s2L[tid][h]);
            biasL[tid] = lsg - 0.5f * sl;
        }
        __syncthreads();
    }

    if (tid < NC) out[(size_t)b * NC + tid] = a2L[tid];
    if (tid < NC * C) {
        const int jj = tid / C, h = tid % C;
        out[BQ * NC + ((size_t)b * NC + jj) * C + h] = mu2L[jj][h];
        out[BQ * NC + BQ * NC * C + ((size_t)b * NC + jj) * C + h] = s2L[jj][h];
    }
}

// ---------------------------------------------------------------------------
extern "C" void kernel_launch(void* const* d_in, const int* in_sizes, int n_in,
                              void* d_out, int out_size, void* d_ws, size_t ws_size,
                              hipStream_t stream)
{
    (void)in_sizes; (void)n_in; (void)out_size; (void)ws_size;
    const float* mask      = (const float*)d_in[0];
    const float* embs      = (const float*)d_in[1];
    const float* depth_emb = (const float*)d_in[2];
    const float* ln_w      = (const float*)d_in[3];
    const float* ln_b      = (const float*)d_in[4];
    const float* dp_w      = (const float*)d_in[5];
    const float* dp_b      = (const float*)d_in[6];
    const float* W1        = (const float*)d_in[7];
    const float* B1        = (const float*)d_in[8];
    const float* bu1       = (const float*)d_in[9];
    const float* bi1       = (const float*)d_in[10];
    const float* W2        = (const float*)d_in[11];
    const float* B2        = (const float*)d_in[12];
    const float* bu2       = (const float*)d_in[13];
    const float* bi2       = (const float*)d_in[14];
    float* out = (float*)d_out;

    // workspace layout (floats), ~219.4 MB
    float* ws = (float*)d_ws;
    size_t o = 0;
    float* V     = ws + o; o += (size_t)NROWS * 1024;   // 54,525,952 (V; mu lives in cols 960..1023 pre-k1b)
    float* wext  = ws + o; o += 81920;
    float* W1m   = ws + o; o += 65536;
    float* c1t   = ws + o; o += 64;
    float* c2t   = ws + o; o += 64;
    float* dwt   = ws + o; o += 832;
    float* sde1  = ws + o; o += 16;
    float* sde2  = ws + o; o += 16;
    float* Smu   = ws + o; o += (size_t)BQ * P * C;     // contiguous with SV2, Dsum (one memset)
    float* SV2   = ws + o; o += (size_t)BQ * P * C;
    float* Dsum  = ws + o; o += (size_t)BQ * P;
    float* muo   = ws + o; o += (size_t)BQ * P * C;
    float* ivv   = ws + o; o += (size_t)BQ * P * C;
    float* c1v   = ws + o; o += (size_t)BQ * P * C;
    float* c0v   = ws + o; o += (size_t)BQ * P;
    float* a1    = ws + o; o += (size_t)BQ * P;
    float* sumfa = ws + o; o += BQ;

    k0_pre<<<653, 256, 0, stream>>>(ln_w, ln_b, dp_w, dp_b, depth_emb, W1,
                                    wext, W1m, c1t, c2t, dwt, sde1, sde2);
    k_sumfa<<<BQ, 128, 0, stream>>>(mask, sumfa);
    hipMemsetAsync(Smu, 0, (size_t)(2 * BQ * P * C + BQ * P) * sizeof(float), stream);
    k1a<<<NROWS / 256, 256, 0, stream>>>(embs, wext, c1t, c2t, dwt, sde1, sde2, V);
    k1b<<<NROWS / 16, 256, 0, stream>>>(W1m, B1, V);
    for (int it = 0; it < 3; ++it) {
        k2_pass<<<BQ * (NI / 64), 256, 0, stream>>>(V, mask, c1v, ivv, c0v,
                                                    Smu, SV2, Dsum, it);
        k2f<<<(BQ * P) / 256, 256, 0, stream>>>(Smu, SV2, Dsum, sumfa, bu1, bi1,
                                                muo, ivv, c1v, c0v, a1);
    }
    k3_routing2<<<BQ, 256, 0, stream>>>(muo, a1, W2, B2, bu2, bi2, out);
}

// Round 4
// 1085.016 us; speedup vs baseline: 1.1115x; 1.1115x over previous
//
#include <hip/hip_runtime.h>
#include <hip/hip_bf16.h>

// Problem dims (fixed by setup_inputs)
constexpr int BQ = 32;          // batch
constexpr int TT = 128;         // tokens
constexpr int DD = 13;          // depth
constexpr int E  = 1024;        // d_emb
constexpr int P  = 64;          // n_parts
constexpr int C  = 16;          // d_cap
constexpr int NC = 5;           // n_classes
constexpr int NI = TT * DD;     // 1664 input capsules (routing 1)
constexpr int NROWS = BQ * NI;  // 53248
constexpr int S1 = 1092;        // k1a xs row stride (floats): skewed layout

// ---------------------------------------------------------------------------
// sumfa[b] = 13 * sum_t mask[b,t]   (fa = sigmoid(logit(m)) = m)
__global__ void k_sumfa(const float* __restrict__ mask, float* __restrict__ sumfa)
{
    const int b = blockIdx.x, tid = threadIdx.x;   // 128 threads
    float v = mask[b * TT + tid];
#pragma unroll
    for (int off = 32; off > 0; off >>= 1) v += __shfl_xor(v, off);
    __shared__ float p2[2];
    if ((tid & 63) == 0) p2[tid >> 6] = v;
    __syncthreads();
    if (tid == 0) sumfa[b] = (float)DD * (p2[0] + p2[1]);
}

// ---------------------------------------------------------------------------
// k0: blocks 0..63: c1t[p]=sum_k g*w, c2t[p]=sum_k b*w + dp_b.
//     blocks 64..319: W1m[d][j*16+h] = W1[j][d][h].
__global__ void k0_pre(const float* __restrict__ ln_w, const float* __restrict__ ln_b,
                       const float* __restrict__ dp_w, const float* __restrict__ dp_b,
                       const float* __restrict__ W1,
                       float* __restrict__ c1t, float* __restrict__ c2t,
                       float* __restrict__ W1m)
{
    const int blk = blockIdx.x, tid = threadIdx.x;
    if (blk < 64) {
        float a0 = 0.f, a1 = 0.f;
        for (int k = tid; k < E; k += 256) {
            const float wv = dp_w[(size_t)blk * E + k];
            a0 = fmaf(ln_w[k], wv, a0);
            a1 = fmaf(ln_b[k], wv, a1);
        }
#pragma unroll
        for (int off = 32; off > 0; off >>= 1) {
            a0 += __shfl_xor(a0, off);
            a1 += __shfl_xor(a1, off);
        }
        __shared__ float r2[2][4];
        if ((tid & 63) == 0) { r2[0][tid >> 6] = a0; r2[1][tid >> 6] = a1; }
        __syncthreads();
        if (tid == 0) {
            c1t[blk] = r2[0][0] + r2[0][1] + r2[0][2] + r2[0][3];
            c2t[blk] = r2[1][0] + r2[1][1] + r2[1][2] + r2[1][3] + dp_b[blk];
        }
    } else {
        const int t = (blk - 64) * 256 + tid;      // < 65536
        const int d = t >> 10, col = t & 1023;
        W1m[t] = W1[((size_t)(col >> 4) * 64 + d) * 16 + (col & 15)];
    }
}

// ---------------------------------------------------------------------------
// k1a: fused LN-stats + GEMM (xfull=embs+de) @ (ln_w*dp_w) -> LN epilogue ->
// swish -> mu written to V[row][960..1023].
// Block = 64 rows (4 rt x 16), 256 threads: thread (c4=tid&15 -> 4 cols,
// q=tid>>4 -> 64-k slice). K-partials combined via shfl_xor(16,32); cross-wave
// partials via hpar (overlaid on xs). xs is skewed (element k of a row lives
// at k + 4*(k>>6)) so the 4 q-groups of a wave hit 4 distinct banks.
__global__ __launch_bounds__(256, 2) void
k1a(const float* __restrict__ embs, const float* __restrict__ depth_emb,
    const float* __restrict__ ln_w, const float* __restrict__ dp_w,
    const float* __restrict__ c1t, const float* __restrict__ c2t,
    float* __restrict__ V)
{
    __shared__ float xs[16 * S1];      // 69.9 KB; hpar [4][16][68] overlays it
    __shared__ float rmean[16], rrstd[16];
    float* hpar = xs;
    const int tid = threadIdx.x;
    const int c4 = tid & 15, q = tid >> 4;
    const int wv = tid >> 6;
    const int row0 = blockIdx.x * 64;

    for (int rt = 0; rt < 4; ++rt) {
        const int r0g = row0 + rt * 16;
        // ---- stage (x + de) + per-row stats
        {
            const int sr = tid >> 4;               // 0..15 row in tile
            const int sk = (tid & 15) * 4;
            const int grow = r0g + sr;
            const float* xr = embs + (size_t)grow * E;
            const float* dr = depth_emb + (size_t)(grow % DD) * E;
            float s = 0.f, s2 = 0.f;
#pragma unroll
            for (int m = 0; m < 16; ++m) {
                const int k = sk + m * 64;
                float4 a = *reinterpret_cast<const float4*>(xr + k);
                const float4 dd = *reinterpret_cast<const float4*>(dr + k);
                a.x += dd.x; a.y += dd.y; a.z += dd.z; a.w += dd.w;
                *reinterpret_cast<float4*>(xs + sr * S1 + sk + m * 68) = a;
                s += a.x + a.y + a.z + a.w;
                s2 = fmaf(a.x, a.x, fmaf(a.y, a.y, fmaf(a.z, a.z, fmaf(a.w, a.w, s2))));
            }
#pragma unroll
            for (int off = 8; off > 0; off >>= 1) {
                s += __shfl_xor(s, off);
                s2 += __shfl_xor(s2, off);
            }
            if ((tid & 15) == 0) {
                const float mean = s * (1.f / E);
                const float var = s2 * (1.f / E) - mean * mean;
                rmean[sr] = mean;
                rrstd[sr] = rsqrtf(var + 1e-5f);
            }
        }
        __syncthreads();
        // ---- GEMM: acc[r][cc] over thread's 64-k slice
        float acc[16][4];
#pragma unroll
        for (int r = 0; r < 16; ++r)
#pragma unroll
            for (int cc = 0; cc < 4; ++cc) acc[r][cc] = 0.f;

        for (int sub = 0; sub < 4; ++sub) {
            const int kb = q * 64 + sub * 16;
            float4 wr_[4][4];
            {
                float4 lw[4];
#pragma unroll
                for (int f = 0; f < 4; ++f)
                    lw[f] = *reinterpret_cast<const float4*>(ln_w + kb + f * 4);
#pragma unroll
                for (int cc = 0; cc < 4; ++cc) {
                    const float* wp = dp_w + (size_t)(c4 * 4 + cc) * E + kb;
#pragma unroll
                    for (int f = 0; f < 4; ++f) {
                        float4 t = *reinterpret_cast<const float4*>(wp + f * 4);
                        t.x *= lw[f].x; t.y *= lw[f].y; t.z *= lw[f].z; t.w *= lw[f].w;
                        wr_[cc][f] = t;
                    }
                }
            }
            const int xbase = q * 68 + sub * 16;   // skewed position of kb
#pragma unroll
            for (int r = 0; r < 16; ++r) {
#pragma unroll
                for (int f = 0; f < 4; ++f) {
                    const float4 x4 = *reinterpret_cast<const float4*>(xs + r * S1 + xbase + f * 4);
#pragma unroll
                    for (int cc = 0; cc < 4; ++cc) {
                        acc[r][cc] = fmaf(x4.x, wr_[cc][f].x, acc[r][cc]);
                        acc[r][cc] = fmaf(x4.y, wr_[cc][f].y, acc[r][cc]);
                        acc[r][cc] = fmaf(x4.z, wr_[cc][f].z, acc[r][cc]);
                        acc[r][cc] = fmaf(x4.w, wr_[cc][f].w, acc[r][cc]);
                    }
                }
            }
        }
        // combine the wave's 4 q-slices
#pragma unroll
        for (int r = 0; r < 16; ++r)
#pragma unroll
            for (int cc = 0; cc < 4; ++cc) {
                float v = acc[r][cc];
                v += __shfl_xor(v, 16);
                v += __shfl_xor(v, 32);
                acc[r][cc] = v;
            }
        __syncthreads();                 // all xs reads done before overlay write
        if ((tid & 48) == 0) {           // lanes 0..15 of each wave
#pragma unroll
            for (int r = 0; r < 16; ++r)
                *reinterpret_cast<float4*>(hpar + ((wv * 16 + r) * 68 + c4 * 4)) =
                    make_float4(acc[r][0], acc[r][1], acc[r][2], acc[r][3]);
        }
        __syncthreads();
        // ---- epilogue: sum 4 wave-partials, LN-affine, swish, store mu
        {
            const int er = tid >> 4, ec = tid & 15;
            float4 sum = make_float4(0.f, 0.f, 0.f, 0.f);
#pragma unroll
            for (int w = 0; w < 4; ++w) {
                const float4 hp = *reinterpret_cast<const float4*>(hpar + ((w * 16 + er) * 68 + ec * 4));
                sum.x += hp.x; sum.y += hp.y; sum.z += hp.z; sum.w += hp.w;
            }
            const float mean = rmean[er], rstd = rrstd[er];
            const float4 cv1 = *reinterpret_cast<const float4*>(c1t + ec * 4);
            const float4 cv2 = *reinterpret_cast<const float4*>(c2t + ec * 4);
            float4 h, mu;
            h.x = fmaf(rstd, sum.x - mean * cv1.x, cv2.x);
            h.y = fmaf(rstd, sum.y - mean * cv1.y, cv2.y);
            h.z = fmaf(rstd, sum.z - mean * cv1.z, cv2.z);
            h.w = fmaf(rstd, sum.w - mean * cv1.w, cv2.w);
            mu.x = h.x / (1.f + __expf(-h.x));
            mu.y = h.y / (1.f + __expf(-h.y));
            mu.z = h.z / (1.f + __expf(-h.z));
            mu.w = h.w / (1.f + __expf(-h.w));
            *reinterpret_cast<float4*>(V + (size_t)(r0g + er) * 1024 + 960 + ec * 4) = mu;
        }
        __syncthreads();
    }
}

// ---------------------------------------------------------------------------
// k1b: V[row][col] = sum_d mu[row][d]*W1m[d][col] + B1[col], col=j*16+h.
// 16 rows/block; mu read from V cols 960..1023 (overwritten after staging).
__global__ __launch_bounds__(256) void
k1b(const float* __restrict__ W1m, const float* __restrict__ B1, float* __restrict__ V)
{
    __shared__ float muL[16][64];
    const int tid = threadIdx.x;
    const int row0 = blockIdx.x * 16;
#pragma unroll
    for (int q = 0; q < 4; ++q) {
        const int idx = q * 256 + tid;
        muL[idx >> 6][idx & 63] = V[(size_t)(row0 + (idx >> 6)) * 1024 + 960 + (idx & 63)];
    }
    __syncthreads();
    const int c4 = tid;   // col-quad 0..255
    float4 acc[16];
    const float4 bv = *reinterpret_cast<const float4*>(B1 + c4 * 4);
#pragma unroll
    for (int r = 0; r < 16; ++r) acc[r] = bv;

    for (int kc = 0; kc < 64; kc += 8) {
        float4 wreg[8];
#pragma unroll
        for (int kk = 0; kk < 8; ++kk)
            wreg[kk] = *reinterpret_cast<const float4*>(W1m + (size_t)(kc + kk) * 1024 + c4 * 4);
#pragma unroll
        for (int r = 0; r < 16; ++r) {
            const float4 ma = *reinterpret_cast<const float4*>(&muL[r][kc]);
            const float4 mb = *reinterpret_cast<const float4*>(&muL[r][kc + 4]);
            float4 a = acc[r];
            a.x = fmaf(ma.x, wreg[0].x, a.x); a.y = fmaf(ma.x, wreg[0].y, a.y);
            a.z = fmaf(ma.x, wreg[0].z, a.z); a.w = fmaf(ma.x, wreg[0].w, a.w);
            a.x = fmaf(ma.y, wreg[1].x, a.x); a.y = fmaf(ma.y, wreg[1].y, a.y);
            a.z = fmaf(ma.y, wreg[1].z, a.z); a.w = fmaf(ma.y, wreg[1].w, a.w);
            a.x = fmaf(ma.z, wreg[2].x, a.x); a.y = fmaf(ma.z, wreg[2].y, a.y);
            a.z = fmaf(ma.z, wreg[2].z, a.z); a.w = fmaf(ma.z, wreg[2].w, a.w);
            a.x = fmaf(ma.w, wreg[3].x, a.x); a.y = fmaf(ma.w, wreg[3].y, a.y);
            a.z = fmaf(ma.w, wreg[3].z, a.z); a.w = fmaf(ma.w, wreg[3].w, a.w);
            a.x = fmaf(mb.x, wreg[4].x, a.x); a.y = fmaf(mb.x, wreg[4].y, a.y);
            a.z = fmaf(mb.x, wreg[4].z, a.z); a.w = fmaf(mb.x, wreg[4].w, a.w);
            a.x = fmaf(mb.y, wreg[5].x, a.x); a.y = fmaf(mb.y, wreg[5].y, a.y);
            a.z = fmaf(mb.y, wreg[5].z, a.z); a.w = fmaf(mb.y, wreg[5].w, a.w);
            a.x = fmaf(mb.z, wreg[6].x, a.x); a.y = fmaf(mb.z, wreg[6].y, a.y);
            a.z = fmaf(mb.z, wreg[6].z, a.z); a.w = fmaf(mb.z, wreg[6].w, a.w);
            a.x = fmaf(mb.w, wreg[7].x, a.x); a.y = fmaf(mb.w, wreg[7].y, a.y);
            a.z = fmaf(mb.w, wreg[7].z, a.z); a.w = fmaf(mb.w, wreg[7].w, a.w);
            acc[r] = a;
        }
    }
#pragma unroll
    for (int r = 0; r < 16; ++r)
        *reinterpret_cast<float4*>(V + (size_t)(row0 + r) * 1024 + c4 * 4) = acc[r];
}

// ---------------------------------------------------------------------------
// kG: Gram accumulation for it0: G[b] += sum_i fa_i mu_i mu_i^T, F[b] += fa mu.
// Grid (b, 64-i chunk) = 832 blocks. Thread owns strided 4x4 tile of G.
__global__ __launch_bounds__(256) void
kG(const float* __restrict__ V, const float* __restrict__ mask,
   float* __restrict__ G, float* __restrict__ F)
{
    __shared__ float mus[64][65];
    __shared__ float faL[64];
    const int tid = threadIdx.x;
    const int b = blockIdx.x / 26, ch = blockIdx.x % 26;
    const int i0 = ch * 64;
#pragma unroll
    for (int s = 0; s < 16; ++s) {
        const int idx = s * 256 + tid;
        mus[idx >> 6][idx & 63] =
            V[(size_t)(b * NI + i0 + (idx >> 6)) * 1024 + 960 + (idx & 63)];
    }
    if (tid < 64) faL[tid] = mask[b * TT + (i0 + tid) / DD];
    __syncthreads();
    const int a0 = tid & 15, b0 = tid >> 4;
    float g[4][4];
    float f4[4] = {0.f, 0.f, 0.f, 0.f};
#pragma unroll
    for (int aa = 0; aa < 4; ++aa)
#pragma unroll
        for (int bb = 0; bb < 4; ++bb) g[aa][bb] = 0.f;
    for (int i = 0; i < 64; ++i) {
        const float fa = faL[i];
        float va[4], vb[4];
#pragma unroll
        for (int s = 0; s < 4; ++s) {
            va[s] = fa * mus[i][a0 + s * 16];
            vb[s] = mus[i][b0 + s * 16];
        }
#pragma unroll
        for (int aa = 0; aa < 4; ++aa)
#pragma unroll
            for (int bb = 0; bb < 4; ++bb) g[aa][bb] = fmaf(va[aa], vb[bb], g[aa][bb]);
        if (b0 == 0) {
#pragma unroll
            for (int aa = 0; aa < 4; ++aa) f4[aa] += va[aa];
        }
    }
#pragma unroll
    for (int aa = 0; aa < 4; ++aa)
#pragma unroll
        for (int bb = 0; bb < 4; ++bb)
            atomicAdd(&G[((size_t)b << 12) + (size_t)(a0 + aa * 16) * 64 + (b0 + bb * 16)],
                      g[aa][bb]);
    if (b0 == 0) {
#pragma unroll
        for (int aa = 0; aa < 4; ++aa) atomicAdd(&F[b * 64 + aa * 16 + a0], f4[aa]);
    }
}

// ---------------------------------------------------------------------------
// kGf: it0 stats analytically (R uniform): per (b, col=j*16+h):
//  Smu = (F.w + sumfa*B1)/64, SV2 = (w^T G w + 2 B1 (F.w) + sumfa B1^2)/64,
//  Dsum = sumfa/64. Grid = 32 b x 4 col-passes.
__global__ __launch_bounds__(256) void
kGf(const float* __restrict__ G, const float* __restrict__ F,
    const float* __restrict__ sumfa, const float* __restrict__ W1m,
    const float* __restrict__ B1, float* __restrict__ Smu,
    float* __restrict__ SV2, float* __restrict__ Dsum)
{
    __shared__ float Gm[64][65];
    __shared__ float Fm[64];
    const int b = blockIdx.x >> 2, p = blockIdx.x & 3;
    const int tid = threadIdx.x;
#pragma unroll
    for (int s = 0; s < 16; ++s) {
        const int idx = s * 256 + tid;
        Gm[idx >> 6][idx & 63] = G[((size_t)b << 12) + idx];
    }
    if (tid < 64) Fm[tid] = F[b * 64 + tid];
    __syncthreads();
    const int col = p * 256 + tid;
    float w[64];
#pragma unroll
    for (int d = 0; d < 64; ++d) w[d] = W1m[d * 1024 + col];
    float fw = 0.f;
#pragma unroll
    for (int d = 0; d < 64; ++d) fw = fmaf(Fm[d], w[d], fw);
    float quad = 0.f;
#pragma unroll
    for (int d1 = 0; d1 < 64; ++d1) {
        float t1 = 0.f;
#pragma unroll
        for (int d2 = 0; d2 < 64; ++d2) t1 = fmaf(Gm[d1][d2], w[d2], t1);
        quad = fmaf(w[d1], t1, quad);
    }
    const float sf = sumfa[b];
    const float b1 = B1[col];
    Smu[((size_t)b << 10) + col] = (fw + sf * b1) * (1.f / 64.f);
    SV2[((size_t)b << 10) + col] = (quad + 2.f * b1 * fw + sf * b1 * b1) * (1.f / 64.f);
    if (p == 0 && tid < 64) Dsum[b * 64 + tid] = sf * (1.f / 64.f);
}

// ---------------------------------------------------------------------------
// k2: one routing-1 pass over V ([i][j*16+h] layout). Block=(b, 64-i tile),
// lane=j, wave=16 i. Named-register pipeline (no arrays -> no scratch).
__global__ __launch_bounds__(256) void
k2_pass(const float* __restrict__ V, const float* __restrict__ mask,
        const float* __restrict__ c1v, const float* __restrict__ ivv,
        const float* __restrict__ c0v, float* __restrict__ Smu,
        float* __restrict__ SV2, float* __restrict__ Dsum, const int it)
{
    __shared__ float lacc[P][34];
    const int tid = threadIdx.x, wave = tid >> 6, j = tid & 63;
    const int b = blockIdx.x / (NI / 64);
    const int tile = blockIdx.x % (NI / 64);
    for (int k = tid; k < P * 34; k += 256) (&lacc[0][0])[k] = 0.f;

    float4 C1a, C1b, C1c, C1d, IVa, IVb, IVc, IVd;
    float c0 = 0.f;
    C1a = C1b = C1c = C1d = IVa = IVb = IVc = IVd = make_float4(0.f, 0.f, 0.f, 0.f);
    if (it > 0) {
        const float4* cp = reinterpret_cast<const float4*>(c1v + ((size_t)b * P + j) * C);
        const float4* ip = reinterpret_cast<const float4*>(ivv + ((size_t)b * P + j) * C);
        C1a = cp[0]; C1b = cp[1]; C1c = cp[2]; C1d = cp[3];
        IVa = ip[0]; IVb = ip[1]; IVc = ip[2]; IVd = ip[3];
        c0 = c0v[(size_t)b * P + j];
    }
    const int i0 = tile * 64 + wave * 16;
    const float* vb = V + ((size_t)(b * NI) + i0) * 1024 + (j << 4);
    const float* mrow = mask + b * TT;

    float4 SMa, SMb, SMc, SMd, Qa, Qb, Qc, Qd;
    SMa = SMb = SMc = SMd = Qa = Qb = Qc = Qd = make_float4(0.f, 0.f, 0.f, 0.f);
    float dsum = 0.f;
    __syncthreads();

    auto proc = [&](const float4 va, const float4 vB, const float4 vc, const float4 vd, const int i) {
        float w;
        const float fam = mrow[i / DD];
        if (it > 0) {
            float q = c0;
            q = fmaf(va.x, fmaf(-va.x, IVa.x, C1a.x), q);
            q = fmaf(va.y, fmaf(-va.y, IVa.y, C1a.y), q);
            q = fmaf(va.z, fmaf(-va.z, IVa.z, C1a.z), q);
            q = fmaf(va.w, fmaf(-va.w, IVa.w, C1a.w), q);
            q = fmaf(vB.x, fmaf(-vB.x, IVb.x, C1b.x), q);
            q = fmaf(vB.y, fmaf(-vB.y, IVb.y, C1b.y), q);
            q = fmaf(vB.z, fmaf(-vB.z, IVb.z, C1b.z), q);
            q = fmaf(vB.w, fmaf(-vB.w, IVb.w, C1b.w), q);
            q = fmaf(vc.x, fmaf(-vc.x, IVc.x, C1c.x), q);
            q = fmaf(vc.y, fmaf(-vc.y, IVc.y, C1c.y), q);
            q = fmaf(vc.z, fmaf(-vc.z, IVc.z, C1c.z), q);
            q = fmaf(vc.w, fmaf(-vc.w, IVc.w, C1c.w), q);
            q = fmaf(vd.x, fmaf(-vd.x, IVd.x, C1d.x), q);
            q = fmaf(vd.y, fmaf(-vd.y, IVd.y, C1d.y), q);
            q = fmaf(vd.z, fmaf(-vd.z, IVd.z, C1d.z), q);
            q = fmaf(vd.w, fmaf(-vd.w, IVd.w, C1d.w), q);
            float m = q;
            m = fmaxf(m, __shfl_xor(m, 32));
            m = fmaxf(m, __shfl_xor(m, 16));
            m = fmaxf(m, __shfl_xor(m, 8));
            m = fmaxf(m, __shfl_xor(m, 4));
            m = fmaxf(m, __shfl_xor(m, 2));
            m = fmaxf(m, __shfl_xor(m, 1));
            const float e = __expf(q - m);
            float ss = e;
            ss += __shfl_xor(ss, 32);
            ss += __shfl_xor(ss, 16);
            ss += __shfl_xor(ss, 8);
            ss += __shfl_xor(ss, 4);
            ss += __shfl_xor(ss, 2);
            ss += __shfl_xor(ss, 1);
            w = fam * (e / ss);
        } else {
            w = fam * (1.f / 64.f);
        }
        dsum += w;
        SMa.x = fmaf(w, va.x, SMa.x); Qa.x = fmaf(w * va.x, va.x, Qa.x);
        SMa.y = fmaf(w, va.y, SMa.y); Qa.y = fmaf(w * va.y, va.y, Qa.y);
        SMa.z = fmaf(w, va.z, SMa.z); Qa.z = fmaf(w * va.z, va.z, Qa.z);
        SMa.w = fmaf(w, va.w, SMa.w); Qa.w = fmaf(w * va.w, va.w, Qa.w);
        SMb.x = fmaf(w, vB.x, SMb.x); Qb.x = fmaf(w * vB.x, vB.x, Qb.x);
        SMb.y = fmaf(w, vB.y, SMb.y); Qb.y = fmaf(w * vB.y, vB.y, Qb.y);
        SMb.z = fmaf(w, vB.z, SMb.z); Qb.z = fmaf(w * vB.z, vB.z, Qb.z);
        SMb.w = fmaf(w, vB.w, SMb.w); Qb.w = fmaf(w * vB.w, vB.w, Qb.w);
        SMc.x = fmaf(w, vc.x, SMc.x); Qc.x = fmaf(w * vc.x, vc.x, Qc.x);
        SMc.y = fmaf(w, vc.y, SMc.y); Qc.y = fmaf(w * vc.y, vc.y, Qc.y);
        SMc.z = fmaf(w, vc.z, SMc.z); Qc.z = fmaf(w * vc.z, vc.z, Qc.z);
        SMc.w = fmaf(w, vc.w, SMc.w); Qc.w = fmaf(w * vc.w, vc.w, Qc.w);
        SMd.x = fmaf(w, vd.x, SMd.x); Qd.x = fmaf(w * vd.x, vd.x, Qd.x);
        SMd.y = fmaf(w, vd.y, SMd.y); Qd.y = fmaf(w * vd.y, vd.y, Qd.y);
        SMd.z = fmaf(w, vd.z, SMd.z); Qd.z = fmaf(w * vd.z, vd.z, Qd.z);
        SMd.w = fmaf(w, vd.w, SMd.w); Qd.w = fmaf(w * vd.w, vd.w, Qd.w);
    };

    float4 A0, A1, A2, A3, B0, B1r, B2, B3;
    {
        const float4* p = reinterpret_cast<const float4*>(vb);
        A0 = p[0]; A1 = p[1]; A2 = p[2]; A3 = p[3];
    }
#pragma unroll
    for (int ss = 0; ss < 16; ss += 2) {
        {
            const float4* p = reinterpret_cast<const float4*>(vb + (size_t)(ss + 1) * 1024);
            B0 = p[0]; B1r = p[1]; B2 = p[2]; B3 = p[3];
        }
        proc(A0, A1, A2, A3, i0 + ss);
        if (ss + 2 < 16) {
            const float4* p = reinterpret_cast<const float4*>(vb + (size_t)(ss + 2) * 1024);
            A0 = p[0]; A1 = p[1]; A2 = p[2]; A3 = p[3];
        }
        proc(B0, B1r, B2, B3, i0 + ss + 1);
    }

    atomicAdd(&lacc[j][0],  SMa.x); atomicAdd(&lacc[j][1],  SMa.y);
    atomicAdd(&lacc[j][2],  SMa.z); atomicAdd(&lacc[j][3],  SMa.w);
    atomicAdd(&lacc[j][4],  SMb.x); atomicAdd(&lacc[j][5],  SMb.y);
    atomicAdd(&lacc[j][6],  SMb.z); atomicAdd(&lacc[j][7],  SMb.w);
    atomicAdd(&lacc[j][8],  SMc.x); atomicAdd(&lacc[j][9],  SMc.y);
    atomicAdd(&lacc[j][10], SMc.z); atomicAdd(&lacc[j][11], SMc.w);
    atomicAdd(&lacc[j][12], SMd.x); atomicAdd(&lacc[j][13], SMd.y);
    atomicAdd(&lacc[j][14], SMd.z); atomicAdd(&lacc[j][15], SMd.w);
    atomicAdd(&lacc[j][16], Qa.x);  atomicAdd(&lacc[j][17], Qa.y);
    atomicAdd(&lacc[j][18], Qa.z);  atomicAdd(&lacc[j][19], Qa.w);
    atomicAdd(&lacc[j][20], Qb.x);  atomicAdd(&lacc[j][21], Qb.y);
    atomicAdd(&lacc[j][22], Qb.z);  atomicAdd(&lacc[j][23], Qb.w);
    atomicAdd(&lacc[j][24], Qc.x);  atomicAdd(&lacc[j][25], Qc.y);
    atomicAdd(&lacc[j][26], Qc.z);  atomicAdd(&lacc[j][27], Qc.w);
    atomicAdd(&lacc[j][28], Qd.x);  atomicAdd(&lacc[j][29], Qd.y);
    atomicAdd(&lacc[j][30], Qd.z);  atomicAdd(&lacc[j][31], Qd.w);
    atomicAdd(&lacc[j][32], dsum);
    __syncthreads();

    for (int k = tid; k < P * 33; k += 256) {
        const int jj = k / 33, r = k % 33;
        const float v = lacc[jj][r];
        if (r < 16)      atomicAdd(&Smu[((size_t)b * P + jj) * C + r], v);
        else if (r < 32) atomicAdd(&SV2[((size_t)b * P + jj) * C + (r - 16)], v);
        else             atomicAdd(&Dsum[(size_t)b * P + jj], v);
    }
}

// ---------------------------------------------------------------------------
// k2f: finalize one routing-1 iteration; zeroes the accumulators for the next
// pass. iv = 1/(2 sig2), c1 = 2 mu iv, c0 = logsig(a) - 0.5 sum log s2 - sum mu^2 iv.
__global__ void k2f(float* __restrict__ Smu, float* __restrict__ SV2,
                    float* __restrict__ Dsum, const float* __restrict__ sumfa,
                    const float* __restrict__ bu, const float* __restrict__ bi,
                    float* __restrict__ muo, float* __restrict__ ivv,
                    float* __restrict__ c1v, float* __restrict__ c0v,
                    float* __restrict__ a1)
{
    const int t = blockIdx.x * blockDim.x + threadIdx.x;
    if (t >= BQ * P) return;
    const int b = t / P, j = t % P;
    const float ds = Dsum[t];
    const float inv = 1.f / ds;
    const float ao = bu[j] * ds - bi[j] * (sumfa[b] - ds);
    a1[t] = ao;
    const float lsg = (ao < 0.f) ? (ao - log1pf(__expf(ao))) : (-log1pf(__expf(-ao)));
    float sumlog = 0.f, moiv = 0.f;
#pragma unroll
    for (int h = 0; h < C; ++h) {
        const float m = Smu[t * C + h] * inv;
        const float s2 = fmaxf(SV2[t * C + h] * inv - m * m, 0.f) + 1e-5f;
        const float iv = 0.5f / s2;
        muo[t * C + h] = m;
        ivv[t * C + h] = iv;
        c1v[t * C + h] = 2.f * m * iv;
        sumlog += logf(s2);
        moiv += m * m * iv;
        Smu[t * C + h] = 0.f;
        SV2[t * C + h] = 0.f;
    }
    Dsum[t] = 0.f;
    c0v[t] = lsg - 0.5f * sumlog - moiv;
}

// ---------------------------------------------------------------------------
// K3: routing 2 (n_i=64, n_o=5, d=16) entirely inside one block per batch.
__global__ void k3_routing2(const float* __restrict__ muo, const float* __restrict__ a1,
                            const float* __restrict__ W2, const float* __restrict__ B2,
                            const float* __restrict__ bu2, const float* __restrict__ bi2,
                            float* __restrict__ out)
{
    __shared__ float mu1L[P][C];
    __shared__ float faL[P];
    __shared__ float V2L[P][NC][C];
    __shared__ float RL[P][NC];
    __shared__ float mu2L[NC][C];
    __shared__ float s2L[NC][C];
    __shared__ float isL[NC][C];
    __shared__ float dsL[NC];
    __shared__ float biasL[NC];
    __shared__ float a2L[NC];
    __shared__ float sumfa2s;
    const int b = blockIdx.x, tid = threadIdx.x;

    for (int k = tid; k < P * C; k += 256) (&mu1L[0][0])[k] = muo[(size_t)b * P * C + k];
    if (tid < P) {
        const float a = a1[(size_t)b * P + tid];
        faL[tid] = 1.f / (1.f + __expf(-a));
    }
    __syncthreads();
    if (tid == 0) {
        float s = 0.f;
        for (int i = 0; i < P; ++i) s += faL[i];
        sumfa2s = s;
    }
    {
        const int i = tid >> 2, hq = tid & 3;
        for (int jj = 0; jj < NC; ++jj) {
            float4 acc = *reinterpret_cast<const float4*>(B2 + jj * C + hq * 4);
            const float* wp = W2 + ((size_t)(i * NC + jj) * C) * C + hq * 4;
#pragma unroll
            for (int d = 0; d < C; ++d) {
                const float m = mu1L[i][d];
                const float4 w4 = *reinterpret_cast<const float4*>(wp + d * C);
                acc.x += m * w4.x; acc.y += m * w4.y; acc.z += m * w4.z; acc.w += m * w4.w;
            }
            *reinterpret_cast<float4*>(&V2L[i][jj][hq * 4]) = acc;
        }
    }
    __syncthreads();

    for (int it = 0; it < 3; ++it) {
        if (tid < P) {
            const int i = tid;
            if (it == 0) {
#pragma unroll
                for (int jj = 0; jj < NC; ++jj) RL[i][jj] = 1.f / NC;
            } else {
                float sc[NC];
                float m = -3.4e38f;
#pragma unroll
                for (int jj = 0; jj < NC; ++jj) {
                    float q = 0.f;
#pragma unroll
                    for (int h = 0; h < C; ++h) {
                        const float d = V2L[i][jj][h] - mu2L[jj][h];
                        q += d * d * isL[jj][h];
                    }
                    sc[jj] = biasL[jj] - q;
                    m = fmaxf(m, sc[jj]);
                }
                float sum = 0.f;
#pragma unroll
                for (int jj = 0; jj < NC; ++jj) { sc[jj] = __expf(sc[jj] - m); sum += sc[jj]; }
                const float invs = 1.f / sum;
#pragma unroll
                for (int jj = 0; jj < NC; ++jj) RL[i][jj] = sc[jj] * invs;
            }
        }
        __syncthreads();
        if (tid < NC) {
            float ds = 0.f;
            for (int i = 0; i < P; ++i) ds += faL[i] * RL[i][tid];
            dsL[tid] = ds;
        }
        __syncthreads();
        if (tid < NC * C) {
            const int jj = tid / C, h = tid % C;
            float smu = 0.f, sv2 = 0.f;
            for (int i = 0; i < P; ++i) {
                const float w = faL[i] * RL[i][jj];
                const float v = V2L[i][jj][h];
                smu += w * v;
                sv2 += w * v * v;
            }
            const float inv = 1.f / dsL[jj];
            const float m = smu * inv;
            const float s2 = fmaxf(sv2 * inv - m * m, 0.f) + 1e-5f;
            mu2L[jj][h] = m;
            s2L[jj][h] = s2;
            isL[jj][h] = 0.5f / s2;
        }
        __syncthreads();
        if (tid < NC) {
            const float ds = dsL[tid];
            const float ao = bu2[tid] * ds - bi2[tid] * (sumfa2s - ds);
            a2L[tid] = ao;
            const float lsg = (ao < 0.f) ? (ao - log1pf(__expf(ao))) : (-log1pf(__expf(-ao)));
            float sl = 0.f;
#pragma unroll
            for (int h = 0; h < C; ++h) sl += logf(s2L[tid][h]);
            biasL[tid] = lsg - 0.5f * sl;
        }
        __syncthreads();
    }

    if (tid < NC) out[(size_t)b * NC + tid] = a2L[tid];
    if (tid < NC * C) {
        const int jj = tid / C, h = tid % C;
        out[BQ * NC + ((size_t)b * NC + jj) * C + h] = mu2L[jj][h];
        out[BQ * NC + BQ * NC * C + ((size_t)b * NC + jj) * C + h] = s2L[jj][h];
    }
}

// ---------------------------------------------------------------------------
extern "C" void kernel_launch(void* const* d_in, const int* in_sizes, int n_in,
                              void* d_out, int out_size, void* d_ws, size_t ws_size,
                              hipStream_t stream)
{
    (void)in_sizes; (void)n_in; (void)out_size; (void)ws_size;
    const float* mask      = (const float*)d_in[0];
    const float* embs      = (const float*)d_in[1];
    const float* depth_emb = (const float*)d_in[2];
    const float* ln_w      = (const float*)d_in[3];
    const float* ln_b      = (const float*)d_in[4];
    const float* dp_w      = (const float*)d_in[5];
    const float* dp_b      = (const float*)d_in[6];
    const float* W1        = (const float*)d_in[7];
    const float* B1        = (const float*)d_in[8];
    const float* bu1       = (const float*)d_in[9];
    const float* bi1       = (const float*)d_in[10];
    const float* W2        = (const float*)d_in[11];
    const float* B2        = (const float*)d_in[12];
    const float* bu2       = (const float*)d_in[13];
    const float* bi2       = (const float*)d_in[14];
    float* out = (float*)d_out;

    // workspace layout (floats), ~219.6 MB
    float* ws = (float*)d_ws;
    size_t o = 0;
    float* V     = ws + o; o += (size_t)NROWS * 1024;   // mu lives in cols 960..1023 pre-k1b
    float* c1t   = ws + o; o += 64;
    float* c2t   = ws + o; o += 64;
    float* W1m   = ws + o; o += 65536;
    float* G     = ws + o; o += (size_t)BQ * 64 * 64;   // 131072 (contiguous with F: one memset)
    float* F     = ws + o; o += (size_t)BQ * 64;        // 2048
    float* Smu   = ws + o; o += (size_t)BQ * P * C;
    float* SV2   = ws + o; o += (size_t)BQ * P * C;
    float* Dsum  = ws + o; o += (size_t)BQ * P;
    float* muo   = ws + o; o += (size_t)BQ * P * C;
    float* ivv   = ws + o; o += (size_t)BQ * P * C;
    float* c1v   = ws + o; o += (size_t)BQ * P * C;
    float* c0v   = ws + o; o += (size_t)BQ * P;
    float* a1    = ws + o; o += (size_t)BQ * P;
    float* sumfa = ws + o; o += BQ;

    k0_pre<<<320, 256, 0, stream>>>(ln_w, ln_b, dp_w, dp_b, W1, c1t, c2t, W1m);
    k_sumfa<<<BQ, 128, 0, stream>>>(mask, sumfa);
    hipMemsetAsync(G, 0, (size_t)(BQ * 64 * 64 + BQ * 64) * sizeof(float), stream);
    k1a<<<NROWS / 64, 256, 0, stream>>>(embs, depth_emb, ln_w, dp_w, c1t, c2t, V);
    kG<<<BQ * 26, 256, 0, stream>>>(V, mask, G, F);          // reads mu before k1b clobbers
    k1b<<<NROWS / 16, 256, 0, stream>>>(W1m, B1, V);
    kGf<<<BQ * 4, 256, 0, stream>>>(G, F, sumfa, W1m, B1, Smu, SV2, Dsum);
    k2f<<<(BQ * P) / 256, 256, 0, stream>>>(Smu, SV2, Dsum, sumfa, bu1, bi1,
                                            muo, ivv, c1v, c0v, a1);
    for (int it = 1; it < 3; ++it) {
        k2_pass<<<BQ * (NI / 64), 256, 0, stream>>>(V, mask, c1v, ivv, c0v,
                                                    Smu, SV2, Dsum, it);
        k2f<<<(BQ * P) / 256, 256, 0, stream>>>(Smu, SV2, Dsum, sumfa, bu1, bi1,
                                                muo, ivv, c1v, c0v, a1);
    }
    k3_routing2<<<BQ, 256, 0, stream>>>(muo, a1, W2, B2, bu2, bi2, out);
}

// Round 5
// 935.861 us; speedup vs baseline: 1.2887x; 1.1594x over previous
//
#include <hip/hip_runtime.h>
#include <hip/hip_bf16.h>

// Problem dims (fixed by setup_inputs)
constexpr int BQ = 32;          // batch
constexpr int TT = 128;         // tokens
constexpr int DD = 13;          // depth
constexpr int E  = 1024;        // d_emb
constexpr int P  = 64;          // n_parts
constexpr int C  = 16;          // d_cap
constexpr int NC = 5;           // n_classes
constexpr int NI = TT * DD;     // 1664 input capsules (routing 1)
constexpr int NROWS = BQ * NI;  // 53248

// Physical V column layout: pcol = hq*256 + j*4 + m  (logical col = j*16 + hq*4 + m)
// => k2's lane-j float4 loads at vb + s*1024 + hq*256 are 1KB-coalesced per wave.

// ---------------------------------------------------------------------------
// sumfa[b] = 13 * sum_t mask[b,t]   (fa = sigmoid(logit(m)) = m)
__global__ void k_sumfa(const float* __restrict__ mask, float* __restrict__ sumfa)
{
    const int b = blockIdx.x, tid = threadIdx.x;   // 128 threads
    float v = mask[b * TT + tid];
#pragma unroll
    for (int off = 32; off > 0; off >>= 1) v += __shfl_xor(v, off);
    __shared__ float p2[2];
    if ((tid & 63) == 0) p2[tid >> 6] = v;
    __syncthreads();
    if (tid == 0) sumfa[b] = (float)DD * (p2[0] + p2[1]);
}

// ---------------------------------------------------------------------------
// k0: precompute tables.
//  blocks 0..63   : c1t[p]=sum_k g*w, c2t[p]=sum_k b*w + dp_b
//  blocks 64..319 : W1m[d][col] = W1[j][d][h]      (LOGICAL col = j*16+h, for kGf)
//  blocks 320..575: W1mP[d][pcol] = W1[j][d][h]    (PHYSICAL layout, for k1b)
//  blocks 576..831: gwP[kq][p][t] = ln_w[kq*4+t] * dp_w[p][kq*4+t]   (for k1a)
//  blocks 832..835: B1P[pcol] = B1[j*16+h]
__global__ void k0_pre(const float* __restrict__ ln_w, const float* __restrict__ ln_b,
                       const float* __restrict__ dp_w, const float* __restrict__ dp_b,
                       const float* __restrict__ W1, const float* __restrict__ B1,
                       float* __restrict__ c1t, float* __restrict__ c2t,
                       float* __restrict__ W1m, float* __restrict__ W1mP,
                       float* __restrict__ gwP, float* __restrict__ B1P)
{
    const int blk = blockIdx.x, tid = threadIdx.x;
    if (blk < 64) {
        float a0 = 0.f, a1 = 0.f;
        for (int k = tid; k < E; k += 256) {
            const float wv = dp_w[(size_t)blk * E + k];
            a0 = fmaf(ln_w[k], wv, a0);
            a1 = fmaf(ln_b[k], wv, a1);
        }
#pragma unroll
        for (int off = 32; off > 0; off >>= 1) {
            a0 += __shfl_xor(a0, off);
            a1 += __shfl_xor(a1, off);
        }
        __shared__ float r2[2][4];
        if ((tid & 63) == 0) { r2[0][tid >> 6] = a0; r2[1][tid >> 6] = a1; }
        __syncthreads();
        if (tid == 0) {
            c1t[blk] = r2[0][0] + r2[0][1] + r2[0][2] + r2[0][3];
            c2t[blk] = r2[1][0] + r2[1][1] + r2[1][2] + r2[1][3] + dp_b[blk];
        }
    } else if (blk < 320) {
        const int t = (blk - 64) * 256 + tid;      // < 65536
        const int d = t >> 10, col = t & 1023;
        W1m[t] = W1[((size_t)(col >> 4) * 64 + d) * 16 + (col & 15)];
    } else if (blk < 576) {
        const int t = (blk - 320) * 256 + tid;     // < 65536
        const int d = t >> 10, pcol = t & 1023;
        const int hq = pcol >> 8, j = (pcol >> 2) & 63, m = pcol & 3;
        W1mP[t] = W1[((size_t)j * 64 + d) * 16 + hq * 4 + m];
    } else if (blk < 832) {
        const int t = (blk - 576) * 256 + tid;     // < 65536
        const int kq = t >> 8, rem = t & 255, p = rem >> 2, tt = rem & 3;
        const int k = kq * 4 + tt;
        gwP[t] = ln_w[k] * dp_w[(size_t)p * E + k];
    } else {
        const int t = (blk - 832) * 256 + tid;     // < 1024
        const int hq = t >> 8, j = (t >> 2) & 63, m = t & 3;
        B1P[t] = B1[j * 16 + hq * 4 + m];
    }
}

// ---------------------------------------------------------------------------
// k1a: lane = row. Thread streams its whole row (embs+de) -> in-thread LN
// stats; weights gwP are wave-uniform (readfirstlane'd colgroup) -> scalar
// loads; 16 cols/thread in acc. Epilogue: LN-affine + swish, LDS transpose,
// coalesced mu write into V[row][960..1023] (physical cols, staging area).
__global__ __launch_bounds__(256) void
k1a(const float* __restrict__ embs, const float* __restrict__ depth_emb,
    const float* __restrict__ gwP, const float* __restrict__ c1t,
    const float* __restrict__ c2t, float* __restrict__ V)
{
    __shared__ float hs[64][65];
    const int tid = threadIdx.x;
    const int lane = tid & 63;
    const int cg = __builtin_amdgcn_readfirstlane(tid >> 6);   // colgroup 0..3
    const int row0 = blockIdx.x * 64;
    const int row = row0 + lane;
    const float* xr = embs + (size_t)row * E;
    const float* dr = depth_emb + (size_t)(row % DD) * E;

    float acc[16];
#pragma unroll
    for (int c = 0; c < 16; ++c) acc[c] = 0.f;
    float s = 0.f, s2 = 0.f;

#pragma unroll 4
    for (int kq = 0; kq < 256; ++kq) {
        float4 x4 = *reinterpret_cast<const float4*>(xr + kq * 4);
        const float4 d4 = *reinterpret_cast<const float4*>(dr + kq * 4);
        x4.x += d4.x; x4.y += d4.y; x4.z += d4.z; x4.w += d4.w;
        s += x4.x + x4.y + x4.z + x4.w;
        s2 = fmaf(x4.x, x4.x, fmaf(x4.y, x4.y, fmaf(x4.z, x4.z, fmaf(x4.w, x4.w, s2))));
        const float4* wq = reinterpret_cast<const float4*>(gwP + ((size_t)kq << 8) + (cg << 6));
#pragma unroll
        for (int c = 0; c < 16; ++c) {
            const float4 w = wq[c];
            acc[c] = fmaf(x4.x, w.x, acc[c]);
            acc[c] = fmaf(x4.y, w.y, acc[c]);
            acc[c] = fmaf(x4.z, w.z, acc[c]);
            acc[c] = fmaf(x4.w, w.w, acc[c]);
        }
    }
    const float mean = s * (1.f / E);
    const float var  = s2 * (1.f / E) - mean * mean;
    const float rstd = rsqrtf(var + 1e-5f);
#pragma unroll
    for (int c = 0; c < 16; ++c) {
        const int p = cg * 16 + c;
        const float h = fmaf(rstd, acc[c] - mean * c1t[p], c2t[p]);
        hs[lane][p] = h / (1.f + __expf(-h));   // swish
    }
    __syncthreads();
    {
        const int rr = tid >> 2, seg = tid & 3;   // 64 rows x 4 segments of 16
        float* dst = V + (size_t)(row0 + rr) * 1024 + 960 + seg * 16;
#pragma unroll
        for (int m = 0; m < 4; ++m) {
            float4 o;
            o.x = hs[rr][seg * 16 + m * 4 + 0];
            o.y = hs[rr][seg * 16 + m * 4 + 1];
            o.z = hs[rr][seg * 16 + m * 4 + 2];
            o.w = hs[rr][seg * 16 + m * 4 + 3];
            *reinterpret_cast<float4*>(dst + m * 4) = o;
        }
    }
}

// ---------------------------------------------------------------------------
// k1b: V[row][pcol] = sum_k mu[row][k]*W1mP[k][pcol] + B1P[pcol].
// 16 rows/block, thread = pcol-quad. Weights coalesced from global; mu read
// wave-uniform from V[row][960..1023] (scalar loads). No LDS.
__global__ __launch_bounds__(256) void
k1b(const float* __restrict__ W1mP, const float* __restrict__ B1P, float* __restrict__ V)
{
    const int c4 = threadIdx.x;            // pcol-quad 0..255
    const int row0 = blockIdx.x * 16;
    float4 acc[16];
    const float4 bv = *reinterpret_cast<const float4*>(B1P + (c4 << 2));
#pragma unroll
    for (int r = 0; r < 16; ++r) acc[r] = bv;

#pragma unroll 2
    for (int kq = 0; kq < 16; ++kq) {
        float4 wreg[4];
#pragma unroll
        for (int t = 0; t < 4; ++t)
            wreg[t] = *reinterpret_cast<const float4*>(
                W1mP + (size_t)(kq * 4 + t) * 1024 + (c4 << 2));
#pragma unroll
        for (int r = 0; r < 16; ++r) {
            // mu[row0+r][kq*4 .. +3]: address is wave-uniform -> s_load_dwordx4
            const float4 sm = *reinterpret_cast<const float4*>(
                V + (size_t)(row0 + r) * 1024 + 960 + kq * 4);
            acc[r].x = fmaf(sm.x, wreg[0].x, acc[r].x);
            acc[r].y = fmaf(sm.x, wreg[0].y, acc[r].y);
            acc[r].z = fmaf(sm.x, wreg[0].z, acc[r].z);
            acc[r].w = fmaf(sm.x, wreg[0].w, acc[r].w);
            acc[r].x = fmaf(sm.y, wreg[1].x, acc[r].x);
            acc[r].y = fmaf(sm.y, wreg[1].y, acc[r].y);
            acc[r].z = fmaf(sm.y, wreg[1].z, acc[r].z);
            acc[r].w = fmaf(sm.y, wreg[1].w, acc[r].w);
            acc[r].x = fmaf(sm.z, wreg[2].x, acc[r].x);
            acc[r].y = fmaf(sm.z, wreg[2].y, acc[r].y);
            acc[r].z = fmaf(sm.z, wreg[2].z, acc[r].z);
            acc[r].w = fmaf(sm.z, wreg[2].w, acc[r].w);
            acc[r].x = fmaf(sm.w, wreg[3].x, acc[r].x);
            acc[r].y = fmaf(sm.w, wreg[3].y, acc[r].y);
            acc[r].z = fmaf(sm.w, wreg[3].z, acc[r].z);
            acc[r].w = fmaf(sm.w, wreg[3].w, acc[r].w);
        }
    }
    __syncthreads();   // all mu reads done before any thread overwrites cols 960..1023
#pragma unroll
    for (int r = 0; r < 16; ++r)
        *reinterpret_cast<float4*>(V + (size_t)(row0 + r) * 1024 + (c4 << 2)) = acc[r];
}

// ---------------------------------------------------------------------------
// kG: Gram accumulation for it0: G[b] += sum_i fa_i mu_i mu_i^T, F[b] += fa mu.
__global__ __launch_bounds__(256) void
kG(const float* __restrict__ V, const float* __restrict__ mask,
   float* __restrict__ G, float* __restrict__ F)
{
    __shared__ float mus[64][65];
    __shared__ float faL[64];
    const int tid = threadIdx.x;
    const int b = blockIdx.x / 26, ch = blockIdx.x % 26;
    const int i0 = ch * 64;
#pragma unroll
    for (int s = 0; s < 16; ++s) {
        const int idx = s * 256 + tid;
        mus[idx >> 6][idx & 63] =
            V[(size_t)(b * NI + i0 + (idx >> 6)) * 1024 + 960 + (idx & 63)];
    }
    if (tid < 64) faL[tid] = mask[b * TT + (i0 + tid) / DD];
    __syncthreads();
    const int a0 = tid & 15, b0 = tid >> 4;
    float g[4][4];
    float f4[4] = {0.f, 0.f, 0.f, 0.f};
#pragma unroll
    for (int aa = 0; aa < 4; ++aa)
#pragma unroll
        for (int bb = 0; bb < 4; ++bb) g[aa][bb] = 0.f;
    for (int i = 0; i < 64; ++i) {
        const float fa = faL[i];
        float va[4], vb[4];
#pragma unroll
        for (int s = 0; s < 4; ++s) {
            va[s] = fa * mus[i][a0 + s * 16];
            vb[s] = mus[i][b0 + s * 16];
        }
#pragma unroll
        for (int aa = 0; aa < 4; ++aa)
#pragma unroll
            for (int bb = 0; bb < 4; ++bb) g[aa][bb] = fmaf(va[aa], vb[bb], g[aa][bb]);
        if (b0 == 0) {
#pragma unroll
            for (int aa = 0; aa < 4; ++aa) f4[aa] += va[aa];
        }
    }
#pragma unroll
    for (int aa = 0; aa < 4; ++aa)
#pragma unroll
        for (int bb = 0; bb < 4; ++bb)
            atomicAdd(&G[((size_t)b << 12) + (size_t)(a0 + aa * 16) * 64 + (b0 + bb * 16)],
                      g[aa][bb]);
    if (b0 == 0) {
#pragma unroll
        for (int aa = 0; aa < 4; ++aa) atomicAdd(&F[b * 64 + aa * 16 + a0], f4[aa]);
    }
}

// ---------------------------------------------------------------------------
// kGf: it0 stats analytically (R uniform) per (b, LOGICAL col):
//  Smu = (F.w + sumfa*B1)/64, SV2 = (w^T G w + 2 B1 (F.w) + sumfa B1^2)/64.
__global__ __launch_bounds__(256) void
kGf(const float* __restrict__ G, const float* __restrict__ F,
    const float* __restrict__ sumfa, const float* __restrict__ W1m,
    const float* __restrict__ B1, float* __restrict__ Smu,
    float* __restrict__ SV2, float* __restrict__ Dsum)
{
    __shared__ float Gm[64][65];
    __shared__ float Fm[64];
    const int b = blockIdx.x >> 2, p = blockIdx.x & 3;
    const int tid = threadIdx.x;
#pragma unroll
    for (int s = 0; s < 16; ++s) {
        const int idx = s * 256 + tid;
        Gm[idx >> 6][idx & 63] = G[((size_t)b << 12) + idx];
    }
    if (tid < 64) Fm[tid] = F[b * 64 + tid];
    __syncthreads();
    const int col = p * 256 + tid;
    float w[64];
#pragma unroll
    for (int d = 0; d < 64; ++d) w[d] = W1m[d * 1024 + col];
    float fw = 0.f;
#pragma unroll
    for (int d = 0; d < 64; ++d) fw = fmaf(Fm[d], w[d], fw);
    float quad = 0.f;
#pragma unroll
    for (int d1 = 0; d1 < 64; ++d1) {
        float t1 = 0.f;
#pragma unroll
        for (int d2 = 0; d2 < 64; ++d2) t1 = fmaf(Gm[d1][d2], w[d2], t1);
        quad = fmaf(w[d1], t1, quad);
    }
    const float sf = sumfa[b];
    const float b1 = B1[col];
    Smu[((size_t)b << 10) + col] = (fw + sf * b1) * (1.f / 64.f);
    SV2[((size_t)b << 10) + col] = (quad + 2.f * b1 * fw + sf * b1 * b1) * (1.f / 64.f);
    if (p == 0 && tid < 64) Dsum[b * 64 + tid] = sf * (1.f / 64.f);
}

// ---------------------------------------------------------------------------
// k2: one routing-1 pass over V (physical layout [i][hq][j][4]). Block =
// (b, 64-i tile), lane = j. Fully-coalesced 1KB b128 loads, named-register
// pipeline. Quad form expanded: sc = c0 + sum_h va*(c1 - va*iv).
__global__ __launch_bounds__(256) void
k2_pass(const float* __restrict__ V, const float* __restrict__ mask,
        const float* __restrict__ c1v, const float* __restrict__ ivv,
        const float* __restrict__ c0v, float* __restrict__ Smu,
        float* __restrict__ SV2, float* __restrict__ Dsum, const int it)
{
    __shared__ float lacc[P][34];
    const int tid = threadIdx.x, wave = tid >> 6, j = tid & 63;
    const int b = blockIdx.x / (NI / 64);
    const int tile = blockIdx.x % (NI / 64);
    for (int k = tid; k < P * 34; k += 256) (&lacc[0][0])[k] = 0.f;

    float4 C1a, C1b, C1c, C1d, IVa, IVb, IVc, IVd;
    float c0 = 0.f;
    C1a = C1b = C1c = C1d = IVa = IVb = IVc = IVd = make_float4(0.f, 0.f, 0.f, 0.f);
    if (it > 0) {
        const float4* cp = reinterpret_cast<const float4*>(c1v + ((size_t)b * P + j) * C);
        const float4* ip = reinterpret_cast<const float4*>(ivv + ((size_t)b * P + j) * C);
        C1a = cp[0]; C1b = cp[1]; C1c = cp[2]; C1d = cp[3];
        IVa = ip[0]; IVb = ip[1]; IVc = ip[2]; IVd = ip[3];
        c0 = c0v[(size_t)b * P + j];
    }
    const int i0 = tile * 64 + wave * 16;
    const float* vb = V + ((size_t)(b * NI) + i0) * 1024 + (j << 2);
    const float* mrow = mask + b * TT;

    float4 SMa, SMb, SMc, SMd, Qa, Qb, Qc, Qd;
    SMa = SMb = SMc = SMd = Qa = Qb = Qc = Qd = make_float4(0.f, 0.f, 0.f, 0.f);
    float dsum = 0.f;
    __syncthreads();

    auto proc = [&](const float4 va, const float4 vB, const float4 vc, const float4 vd, const int i) {
        float w;
        const float fam = mrow[i / DD];
        if (it > 0) {
            float q = c0;
            q = fmaf(va.x, fmaf(-va.x, IVa.x, C1a.x), q);
            q = fmaf(va.y, fmaf(-va.y, IVa.y, C1a.y), q);
            q = fmaf(va.z, fmaf(-va.z, IVa.z, C1a.z), q);
            q = fmaf(va.w, fmaf(-va.w, IVa.w, C1a.w), q);
            q = fmaf(vB.x, fmaf(-vB.x, IVb.x, C1b.x), q);
            q = fmaf(vB.y, fmaf(-vB.y, IVb.y, C1b.y), q);
            q = fmaf(vB.z, fmaf(-vB.z, IVb.z, C1b.z), q);
            q = fmaf(vB.w, fmaf(-vB.w, IVb.w, C1b.w), q);
            q = fmaf(vc.x, fmaf(-vc.x, IVc.x, C1c.x), q);
            q = fmaf(vc.y, fmaf(-vc.y, IVc.y, C1c.y), q);
            q = fmaf(vc.z, fmaf(-vc.z, IVc.z, C1c.z), q);
            q = fmaf(vc.w, fmaf(-vc.w, IVc.w, C1c.w), q);
            q = fmaf(vd.x, fmaf(-vd.x, IVd.x, C1d.x), q);
            q = fmaf(vd.y, fmaf(-vd.y, IVd.y, C1d.y), q);
            q = fmaf(vd.z, fmaf(-vd.z, IVd.z, C1d.z), q);
            q = fmaf(vd.w, fmaf(-vd.w, IVd.w, C1d.w), q);
            float m = q;
            m = fmaxf(m, __shfl_xor(m, 32));
            m = fmaxf(m, __shfl_xor(m, 16));
            m = fmaxf(m, __shfl_xor(m, 8));
            m = fmaxf(m, __shfl_xor(m, 4));
            m = fmaxf(m, __shfl_xor(m, 2));
            m = fmaxf(m, __shfl_xor(m, 1));
            const float e = __expf(q - m);
            float ss = e;
            ss += __shfl_xor(ss, 32);
            ss += __shfl_xor(ss, 16);
            ss += __shfl_xor(ss, 8);
            ss += __shfl_xor(ss, 4);
            ss += __shfl_xor(ss, 2);
            ss += __shfl_xor(ss, 1);
            w = fam * (e / ss);
        } else {
            w = fam * (1.f / 64.f);
        }
        dsum += w;
        SMa.x = fmaf(w, va.x, SMa.x); Qa.x = fmaf(w * va.x, va.x, Qa.x);
        SMa.y = fmaf(w, va.y, SMa.y); Qa.y = fmaf(w * va.y, va.y, Qa.y);
        SMa.z = fmaf(w, va.z, SMa.z); Qa.z = fmaf(w * va.z, va.z, Qa.z);
        SMa.w = fmaf(w, va.w, SMa.w); Qa.w = fmaf(w * va.w, va.w, Qa.w);
        SMb.x = fmaf(w, vB.x, SMb.x); Qb.x = fmaf(w * vB.x, vB.x, Qb.x);
        SMb.y = fmaf(w, vB.y, SMb.y); Qb.y = fmaf(w * vB.y, vB.y, Qb.y);
        SMb.z = fmaf(w, vB.z, SMb.z); Qb.z = fmaf(w * vB.z, vB.z, Qb.z);
        SMb.w = fmaf(w, vB.w, SMb.w); Qb.w = fmaf(w * vB.w, vB.w, Qb.w);
        SMc.x = fmaf(w, vc.x, SMc.x); Qc.x = fmaf(w * vc.x, vc.x, Qc.x);
        SMc.y = fmaf(w, vc.y, SMc.y); Qc.y = fmaf(w * vc.y, vc.y, Qc.y);
        SMc.z = fmaf(w, vc.z, SMc.z); Qc.z = fmaf(w * vc.z, vc.z, Qc.z);
        SMc.w = fmaf(w, vc.w, SMc.w); Qc.w = fmaf(w * vc.w, vc.w, Qc.w);
        SMd.x = fmaf(w, vd.x, SMd.x); Qd.x = fmaf(w * vd.x, vd.x, Qd.x);
        SMd.y = fmaf(w, vd.y, SMd.y); Qd.y = fmaf(w * vd.y, vd.y, Qd.y);
        SMd.z = fmaf(w, vd.z, SMd.z); Qd.z = fmaf(w * vd.z, vd.z, Qd.z);
        SMd.w = fmaf(w, vd.w, SMd.w); Qd.w = fmaf(w * vd.w, vd.w, Qd.w);
    };

    float4 A0, A1, A2, A3, B0, B1r, B2, B3;
    {
        A0 = *reinterpret_cast<const float4*>(vb + 0);
        A1 = *reinterpret_cast<const float4*>(vb + 256);
        A2 = *reinterpret_cast<const float4*>(vb + 512);
        A3 = *reinterpret_cast<const float4*>(vb + 768);
    }
#pragma unroll
    for (int ss = 0; ss < 16; ss += 2) {
        {
            const float* p = vb + (size_t)(ss + 1) * 1024;
            B0 = *reinterpret_cast<const float4*>(p + 0);
            B1r = *reinterpret_cast<const float4*>(p + 256);
            B2 = *reinterpret_cast<const float4*>(p + 512);
            B3 = *reinterpret_cast<const float4*>(p + 768);
        }
        proc(A0, A1, A2, A3, i0 + ss);
        if (ss + 2 < 16) {
            const float* p = vb + (size_t)(ss + 2) * 1024;
            A0 = *reinterpret_cast<const float4*>(p + 0);
            A1 = *reinterpret_cast<const float4*>(p + 256);
            A2 = *reinterpret_cast<const float4*>(p + 512);
            A3 = *reinterpret_cast<const float4*>(p + 768);
        }
        proc(B0, B1r, B2, B3, i0 + ss + 1);
    }

    atomicAdd(&lacc[j][0],  SMa.x); atomicAdd(&lacc[j][1],  SMa.y);
    atomicAdd(&lacc[j][2],  SMa.z); atomicAdd(&lacc[j][3],  SMa.w);
    atomicAdd(&lacc[j][4],  SMb.x); atomicAdd(&lacc[j][5],  SMb.y);
    atomicAdd(&lacc[j][6],  SMb.z); atomicAdd(&lacc[j][7],  SMb.w);
    atomicAdd(&lacc[j][8],  SMc.x); atomicAdd(&lacc[j][9],  SMc.y);
    atomicAdd(&lacc[j][10], SMc.z); atomicAdd(&lacc[j][11], SMc.w);
    atomicAdd(&lacc[j][12], SMd.x); atomicAdd(&lacc[j][13], SMd.y);
    atomicAdd(&lacc[j][14], SMd.z); atomicAdd(&lacc[j][15], SMd.w);
    atomicAdd(&lacc[j][16], Qa.x);  atomicAdd(&lacc[j][17], Qa.y);
    atomicAdd(&lacc[j][18], Qa.z);  atomicAdd(&lacc[j][19], Qa.w);
    atomicAdd(&lacc[j][20], Qb.x);  atomicAdd(&lacc[j][21], Qb.y);
    atomicAdd(&lacc[j][22], Qb.z);  atomicAdd(&lacc[j][23], Qb.w);
    atomicAdd(&lacc[j][24], Qc.x);  atomicAdd(&lacc[j][25], Qc.y);
    atomicAdd(&lacc[j][26], Qc.z);  atomicAdd(&lacc[j][27], Qc.w);
    atomicAdd(&lacc[j][28], Qd.x);  atomicAdd(&lacc[j][29], Qd.y);
    atomicAdd(&lacc[j][30], Qd.z);  atomicAdd(&lacc[j][31], Qd.w);
    atomicAdd(&lacc[j][32], dsum);
    __syncthreads();

    for (int k = tid; k < P * 33; k += 256) {
        const int jj = k / 33, r = k % 33;
        const float v = lacc[jj][r];
        if (r < 16)      atomicAdd(&Smu[((size_t)b * P + jj) * C + r], v);
        else if (r < 32) atomicAdd(&SV2[((size_t)b * P + jj) * C + (r - 16)], v);
        else             atomicAdd(&Dsum[(size_t)b * P + jj], v);
    }
}

// ---------------------------------------------------------------------------
// k2f: finalize one routing-1 iteration; zeroes accumulators for next pass.
__global__ void k2f(float* __restrict__ Smu, float* __restrict__ SV2,
                    float* __restrict__ Dsum, const float* __restrict__ sumfa,
                    const float* __restrict__ bu, const float* __restrict__ bi,
                    float* __restrict__ muo, float* __restrict__ ivv,
                    float* __restrict__ c1v, float* __restrict__ c0v,
                    float* __restrict__ a1)
{
    const int t = blockIdx.x * blockDim.x + threadIdx.x;
    if (t >= BQ * P) return;
    const int b = t / P, j = t % P;
    const float ds = Dsum[t];
    const float inv = 1.f / ds;
    const float ao = bu[j] * ds - bi[j] * (sumfa[b] - ds);
    a1[t] = ao;
    const float lsg = (ao < 0.f) ? (ao - log1pf(__expf(ao))) : (-log1pf(__expf(-ao)));
    float sumlog = 0.f, moiv = 0.f;
#pragma unroll
    for (int h = 0; h < C; ++h) {
        const float m = Smu[t * C + h] * inv;
        const float s2 = fmaxf(SV2[t * C + h] * inv - m * m, 0.f) + 1e-5f;
        const float iv = 0.5f / s2;
        muo[t * C + h] = m;
        ivv[t * C + h] = iv;
        c1v[t * C + h] = 2.f * m * iv;
        sumlog += logf(s2);
        moiv += m * m * iv;
        Smu[t * C + h] = 0.f;
        SV2[t * C + h] = 0.f;
    }
    Dsum[t] = 0.f;
    c0v[t] = lsg - 0.5f * sumlog - moiv;
}

// ---------------------------------------------------------------------------
// K3: routing 2 (n_i=64, n_o=5, d=16) entirely inside one block per batch.
__global__ void k3_routing2(const float* __restrict__ muo, const float* __restrict__ a1,
                            const float* __restrict__ W2, const float* __restrict__ B2,
                            const float* __restrict__ bu2, const float* __restrict__ bi2,
                            float* __restrict__ out)
{
    __shared__ float mu1L[P][C];
    __shared__ float faL[P];
    __shared__ float V2L[P][NC][C];
    __shared__ float RL[P][NC];
    __shared__ float mu2L[NC][C];
    __shared__ float s2L[NC][C];
    __shared__ float isL[NC][C];
    __shared__ float dsL[NC];
    __shared__ float biasL[NC];
    __shared__ float a2L[NC];
    __shared__ float sumfa2s;
    const int b = blockIdx.x, tid = threadIdx.x;

    for (int k = tid; k < P * C; k += 256) (&mu1L[0][0])[k] = muo[(size_t)b * P * C + k];
    if (tid < P) {
        const float a = a1[(size_t)b * P + tid];
        faL[tid] = 1.f / (1.f + __expf(-a));
    }
    __syncthreads();
    if (tid == 0) {
        float s = 0.f;
        for (int i = 0; i < P; ++i) s += faL[i];
        sumfa2s = s;
    }
    {
        const int i = tid >> 2, hq = tid & 3;
        for (int jj = 0; jj < NC; ++jj) {
            float4 acc = *reinterpret_cast<const float4*>(B2 + jj * C + hq * 4);
            const float* wp = W2 + ((size_t)(i * NC + jj) * C) * C + hq * 4;
#pragma unroll
            for (int d = 0; d < C; ++d) {
                const float m = mu1L[i][d];
                const float4 w4 = *reinterpret_cast<const float4*>(wp + d * C);
                acc.x += m * w4.x; acc.y += m * w4.y; acc.z += m * w4.z; acc.w += m * w4.w;
            }
            *reinterpret_cast<float4*>(&V2L[i][jj][hq * 4]) = acc;
        }
    }
    __syncthreads();

    for (int it = 0; it < 3; ++it) {
        if (tid < P) {
            const int i = tid;
            if (it == 0) {
#pragma unroll
                for (int jj = 0; jj < NC; ++jj) RL[i][jj] = 1.f / NC;
            } else {
                float sc[NC];
                float m = -3.4e38f;
#pragma unroll
                for (int jj = 0; jj < NC; ++jj) {
                    float q = 0.f;
#pragma unroll
                    for (int h = 0; h < C; ++h) {
                        const float d = V2L[i][jj][h] - mu2L[jj][h];
                        q += d * d * isL[jj][h];
                    }
                    sc[jj] = biasL[jj] - q;
                    m = fmaxf(m, sc[jj]);
                }
                float sum = 0.f;
#pragma unroll
                for (int jj = 0; jj < NC; ++jj) { sc[jj] = __expf(sc[jj] - m); sum += sc[jj]; }
                const float invs = 1.f / sum;
#pragma unroll
                for (int jj = 0; jj < NC; ++jj) RL[i][jj] = sc[jj] * invs;
            }
        }
        __syncthreads();
        if (tid < NC) {
            float ds = 0.f;
            for (int i = 0; i < P; ++i) ds += faL[i] * RL[i][tid];
            dsL[tid] = ds;
        }
        __syncthreads();
        if (tid < NC * C) {
            const int jj = tid / C, h = tid % C;
            float smu = 0.f, sv2 = 0.f;
            for (int i = 0; i < P; ++i) {
                const float w = faL[i] * RL[i][jj];
                const float v = V2L[i][jj][h];
                smu += w * v;
                sv2 += w * v * v;
            }
            const float inv = 1.f / dsL[jj];
            const float m = smu * inv;
            const float s2 = fmaxf(sv2 * inv - m * m, 0.f) + 1e-5f;
            mu2L[jj][h] = m;
            s2L[jj][h] = s2;
            isL[jj][h] = 0.5f / s2;
        }
        __syncthreads();
        if (tid < NC) {
            const float ds = dsL[tid];
            const float ao = bu2[tid] * ds - bi2[tid] * (sumfa2s - ds);
            a2L[tid] = ao;
            const float lsg = (ao < 0.f) ? (ao - log1pf(__expf(ao))) : (-log1pf(__expf(-ao)));
            float sl = 0.f;
#pragma unroll
            for (int h = 0; h < C; ++h) sl += logf(s2L[tid][h]);
            biasL[tid] = lsg - 0.5f * sl;
        }
        __syncthreads();
    }

    if (tid < NC) out[(size_t)b * NC + tid] = a2L[tid];
    if (tid < NC * C) {
        const int jj = tid / C, h = tid % C;
        out[BQ * NC + ((size_t)b * NC + jj) * C + h] = mu2L[jj][h];
        out[BQ * NC + BQ * NC * C + ((size_t)b * NC + jj) * C + h] = s2L[jj][h];
    }
}

// ---------------------------------------------------------------------------
extern "C" void kernel_launch(void* const* d_in, const int* in_sizes, int n_in,
                              void* d_out, int out_size, void* d_ws, size_t ws_size,
                              hipStream_t stream)
{
    (void)in_sizes; (void)n_in; (void)out_size; (void)ws_size;
    const float* mask      = (const float*)d_in[0];
    const float* embs      = (const float*)d_in[1];
    const float* depth_emb = (const float*)d_in[2];
    const float* ln_w      = (const float*)d_in[3];
    const float* ln_b      = (const float*)d_in[4];
    const float* dp_w      = (const float*)d_in[5];
    const float* dp_b      = (const float*)d_in[6];
    const float* W1        = (const float*)d_in[7];
    const float* B1        = (const float*)d_in[8];
    const float* bu1       = (const float*)d_in[9];
    const float* bi1       = (const float*)d_in[10];
    const float* W2        = (const float*)d_in[11];
    const float* B2        = (const float*)d_in[12];
    const float* bu2       = (const float*)d_in[13];
    const float* bi2       = (const float*)d_in[14];
    float* out = (float*)d_out;

    // workspace layout (floats), ~220 MB
    float* ws = (float*)d_ws;
    size_t o = 0;
    float* V     = ws + o; o += (size_t)NROWS * 1024;   // mu staged in pcols 960..1023 pre-k1b
    float* c1t   = ws + o; o += 64;
    float* c2t   = ws + o; o += 64;
    float* W1m   = ws + o; o += 65536;                  // logical (kGf)
    float* W1mP  = ws + o; o += 65536;                  // physical (k1b)
    float* gwP   = ws + o; o += 65536;                  // [kq][p][4] (k1a)
    float* B1P   = ws + o; o += 1024;
    float* G     = ws + o; o += (size_t)BQ * 64 * 64;   // contiguous with F: one memset
    float* F     = ws + o; o += (size_t)BQ * 64;
    float* Smu   = ws + o; o += (size_t)BQ * P * C;
    float* SV2   = ws + o; o += (size_t)BQ * P * C;
    float* Dsum  = ws + o; o += (size_t)BQ * P;
    float* muo   = ws + o; o += (size_t)BQ * P * C;
    float* ivv   = ws + o; o += (size_t)BQ * P * C;
    float* c1v   = ws + o; o += (size_t)BQ * P * C;
    float* c0v   = ws + o; o += (size_t)BQ * P;
    float* a1    = ws + o; o += (size_t)BQ * P;
    float* sumfa = ws + o; o += BQ;

    k0_pre<<<836, 256, 0, stream>>>(ln_w, ln_b, dp_w, dp_b, W1, B1,
                                    c1t, c2t, W1m, W1mP, gwP, B1P);
    k_sumfa<<<BQ, 128, 0, stream>>>(mask, sumfa);
    hipMemsetAsync(G, 0, (size_t)(BQ * 64 * 64 + BQ * 64) * sizeof(float), stream);
    k1a<<<NROWS / 64, 256, 0, stream>>>(embs, depth_emb, gwP, c1t, c2t, V);
    kG<<<BQ * 26, 256, 0, stream>>>(V, mask, G, F);      // reads mu before k1b clobbers
    k1b<<<NROWS / 16, 256, 0, stream>>>(W1mP, B1P, V);
    kGf<<<BQ * 4, 256, 0, stream>>>(G, F, sumfa, W1m, B1, Smu, SV2, Dsum);
    k2f<<<(BQ * P) / 256, 256, 0, stream>>>(Smu, SV2, Dsum, sumfa, bu1, bi1,
                                            muo, ivv, c1v, c0v, a1);
    for (int it = 1; it < 3; ++it) {
        k2_pass<<<BQ * (NI / 64), 256, 0, stream>>>(V, mask, c1v, ivv, c0v,
                                                    Smu, SV2, Dsum, it);
        k2f<<<(BQ * P) / 256, 256, 0, stream>>>(Smu, SV2, Dsum, sumfa, bu1, bi1,
                                                muo, ivv, c1v, c0v, a1);
    }
    k3_routing2<<<BQ, 256, 0, stream>>>(muo, a1, W2, B2, bu2, bi2, out);
}